// Round 8
// baseline (334.084 us; speedup 1.0000x reference)
//
#include <hip/hip_runtime.h>

#define F 64
#define BN_EPS 1e-5f

static __device__ __forceinline__ float4 f4add(float4 a, float4 b) {
    a.x += b.x; a.y += b.y; a.z += b.z; a.w += b.w; return a;
}

// ---------------- Kernel 1: degree histogram + per-edge rank ----------------
__global__ __launch_bounds__(256) void hist_kernel(
    const int* __restrict__ row,
    const int* __restrict__ col,
    int* __restrict__ counts,   // [N], pre-zeroed
    int* __restrict__ rank,     // [E], coalesced write
    int nEdges)
{
    const int stride = gridDim.x * blockDim.x;
    for (int e = blockIdx.x * blockDim.x + threadIdx.x; e < nEdges; e += stride) {
        const int r = row[e];
        const int c = col[e];
        if (r != c) {
            rank[e] = atomicAdd(&counts[r], 1);
        }
    }
}

// ---------------- Kernel 2a: per-block scan of counts ----------------
__global__ __launch_bounds__(256) void scan1_kernel(
    const int* __restrict__ counts,
    int* __restrict__ starts,       // [N+1]
    int* __restrict__ blocksums,    // [nblocks]
    int n)
{
    __shared__ int tmp[256];
    const int t = threadIdx.x;
    const int i = blockIdx.x * 256 + t;
    const int v = (i < n) ? counts[i] : 0;
    tmp[t] = v;
    __syncthreads();
    for (int off = 1; off < 256; off <<= 1) {
        const int a = (t >= off) ? tmp[t - off] : 0;
        __syncthreads();
        tmp[t] += a;
        __syncthreads();
    }
    if (i < n) starts[i] = tmp[t] - v;     // exclusive within block
    if (t == 255) blocksums[blockIdx.x] = tmp[255];
}

// ---------------- Kernel 2b: scan of block sums (single block) ----------------
__global__ __launch_bounds__(512) void scan2_kernel(
    int* __restrict__ blocksums,
    int* __restrict__ starts,
    int nblocks, int n)
{
    __shared__ int tmp[512];
    const int t = threadIdx.x;
    const int v = (t < nblocks) ? blocksums[t] : 0;
    tmp[t] = v;
    __syncthreads();
    for (int off = 1; off < 512; off <<= 1) {
        const int a = (t >= off) ? tmp[t - off] : 0;
        __syncthreads();
        tmp[t] += a;
        __syncthreads();
    }
    if (t < nblocks) blocksums[t] = tmp[t] - v;   // exclusive
    if (t == 511) starts[n] = tmp[511];           // total kept-edge count
}

// ---------------- Kernel 2c: add block offsets ----------------
__global__ __launch_bounds__(256) void scan3_kernel(
    int* __restrict__ starts,
    const int* __restrict__ blocksums,
    int n)
{
    const int i = blockIdx.x * 256 + threadIdx.x;
    if (i < n) starts[i] += blocksums[i >> 8];
}

// ---------------- Kernel 3: reorder cols into CSR order (no atomics) ----------
__global__ __launch_bounds__(256) void reorder_kernel(
    const int* __restrict__ row,
    const int* __restrict__ col,
    const int* __restrict__ starts,
    const int* __restrict__ rank,
    int* __restrict__ col_sorted,
    int nEdges)
{
    const int stride = gridDim.x * blockDim.x;
    for (int e = blockIdx.x * blockDim.x + threadIdx.x; e < nEdges; e += stride) {
        const int r = row[e];
        const int c = col[e];
        if (r != c) {
            col_sorted[starts[r] + rank[e]] = c;   // fire-and-forget scatter
        }
    }
}

// ---------------- Kernel A: gather-aggregate (float4, direct index loads) -----
__global__ __launch_bounds__(256) void gather_kernel(
    const float4* __restrict__ x4,
    const int* __restrict__ starts,
    const int* __restrict__ col_sorted,
    float4* __restrict__ agg4,     // = d_out viewed as float4
    int nNodes)
{
    const int lane = threadIdx.x & 63;
    const int w = threadIdx.x >> 6;
    const int r = blockIdx.x * 4 + w;
    if (r >= nNodes) return;

    const int g = lane >> 4;   // 0..3
    const int q = lane & 15;   // 0..15

    const int s  = starts[r];
    const int en = starts[r + 1];

    const float4 vself = x4[(size_t)r * 16 + q];

    float4 a0 = {0,0,0,0}, a1 = {0,0,0,0}, a2 = {0,0,0,0}, a3 = {0,0,0,0};

    int e = s;
    for (; e + 16 <= en; e += 16) {
        const int c0 = col_sorted[e + g];
        const int c1 = col_sorted[e + 4 + g];
        const int c2 = col_sorted[e + 8 + g];
        const int c3 = col_sorted[e + 12 + g];
        const float4 t0 = x4[(size_t)c0 * 16 + q];
        const float4 t1 = x4[(size_t)c1 * 16 + q];
        const float4 t2 = x4[(size_t)c2 * 16 + q];
        const float4 t3 = x4[(size_t)c3 * 16 + q];
        a0 = f4add(a0, t0);
        a1 = f4add(a1, t1);
        a2 = f4add(a2, t2);
        a3 = f4add(a3, t3);
    }
    for (; e + 4 <= en; e += 4) {
        const int c = col_sorted[e + g];
        a0 = f4add(a0, x4[(size_t)c * 16 + q]);
    }
    if (e + g < en) {
        const int c = col_sorted[e + g];
        a1 = f4add(a1, x4[(size_t)c * 16 + q]);
    }

    float4 v = f4add(f4add(a0, a1), f4add(a2, a3));
    v.x += __shfl_xor(v.x, 16, 64);
    v.y += __shfl_xor(v.y, 16, 64);
    v.z += __shfl_xor(v.z, 16, 64);
    v.w += __shfl_xor(v.w, 16, 64);
    v.x += __shfl_xor(v.x, 32, 64);
    v.y += __shfl_xor(v.y, 32, 64);
    v.z += __shfl_xor(v.z, 32, 64);
    v.w += __shfl_xor(v.w, 32, 64);
    v = f4add(v, vself);

    if (g == 0) {
        agg4[(size_t)r * 16 + q] = v;
    }
}

// ---------------- Kernel B: split-output MLP (64 nodes/block, 4 waves) --------
// lane = node-within-tile; wave w computes output features [w*16, w*16+16).
// Input staged transposed in padded LDS; h1 exchanged via padded LDS; h2
// transposed back through LDS for fully-coalesced float4 global stores.
// All LDS tiles use [64][65] padding -> worst aliasing is 2-way (free).
__global__ __launch_bounds__(256, 4) void mlp_kernel(
    const float* in_,               // = d_out (agg) — same buffer as out_
    const float* __restrict__ W1,
    const float* __restrict__ b1,
    const float* __restrict__ W2,
    const float* __restrict__ b2,
    float* out_,                    // = d_out (h2)
    int nNodes)
{
    __shared__ float sIn[64][65];   // input transposed [feat][node]; reused for h2
    __shared__ float sH[64][65];    // h1 [feat][node]

    const int tid  = threadIdx.x;
    const int lane = tid & 63;      // node-within-tile
    const int w    = tid >> 6;      // wave id = output-feature chunk
    const int t0   = blockIdx.x * 64;
    const float4* in4 = (const float4*)in_;

    // ---- stage: 64 nodes x 64 feats, transposed ----
    #pragma unroll
    for (int i = 0; i < 4; ++i) {
        const int flat = i * 256 + tid;     // 0..1023
        const int node = flat >> 4;         // 0..63
        const int quad = flat & 15;         // 0..15
        int nn = t0 + node;
        if (nn >= nNodes) nn = nNodes - 1;  // clamp (dup, discarded at store)
        const float4 vv = in4[(size_t)nn * 16 + quad];
        sIn[quad * 4 + 0][node] = vv.x;
        sIn[quad * 4 + 1][node] = vv.y;
        sIn[quad * 4 + 2][node] = vv.z;
        sIn[quad * 4 + 3][node] = vv.w;
    }
    __syncthreads();

    // ---- layer 1: wave w -> h1[w*16+j][all nodes] ----
    float acc[16];
    #pragma unroll
    for (int j = 0; j < 16; ++j) acc[j] = b1[w * 16 + j];
    for (int k = 0; k < 64; ++k) {
        const float vk = sIn[k][lane];
        const float* wr = &W1[k * 64 + w * 16];      // wave-uniform -> s_load
        #pragma unroll
        for (int j = 0; j < 16; ++j) acc[j] = fmaf(vk, wr[j], acc[j]);
    }
    #pragma unroll
    for (int j = 0; j < 16; ++j) sH[w * 16 + j][lane] = fmaxf(acc[j], 0.0f);
    __syncthreads();                                 // also: sIn reads done

    // ---- layer 2: wave w -> h2[w*16+j][all nodes] ----
    float acc2[16];
    #pragma unroll
    for (int j = 0; j < 16; ++j) acc2[j] = b2[w * 16 + j];
    for (int k = 0; k < 64; ++k) {
        const float hk = sH[k][lane];
        const float* wr = &W2[k * 64 + w * 16];      // wave-uniform -> s_load
        #pragma unroll
        for (int j = 0; j < 16; ++j) acc2[j] = fmaf(hk, wr[j], acc2[j]);
    }
    #pragma unroll
    for (int j = 0; j < 16; ++j) sIn[w * 16 + j][lane] = fmaxf(acc2[j], 0.0f);
    __syncthreads();

    // ---- cooperative coalesced store: 1 KB/instr linear float4 ----
    float4* out4 = (float4*)out_;
    const int base4 = t0 * 16;                       // tile start in float4 units
    const int lim4  = nNodes * 16;
    #pragma unroll
    for (int i = 0; i < 4; ++i) {
        const int idx4 = i * 256 + tid;              // 0..1023 within tile
        const int node = idx4 >> 4;                  // 0..63
        const int f0   = (idx4 & 15) * 4;            // feature quad
        if (base4 + idx4 < lim4) {
            float4 vv;
            vv.x = sIn[f0 + 0][node];
            vv.y = sIn[f0 + 1][node];
            vv.z = sIn[f0 + 2][node];
            vv.w = sIn[f0 + 3][node];
            out4[base4 + idx4] = vv;
        }
    }
}

// ---------------- Kernel C1: BN stats (sum / sumsq per feature) ---------------
__global__ __launch_bounds__(256) void stats_kernel(
    const float4* __restrict__ h,
    float* __restrict__ stats,      // [0..63]=sum, [64..127]=sumsq, pre-zeroed
    int total4)
{
    float4 ps = {0,0,0,0}, pq = {0,0,0,0};
    const int stride = gridDim.x * blockDim.x;   // multiple of 16
    for (int i = blockIdx.x * blockDim.x + threadIdx.x; i < total4; i += stride) {
        const float4 v = h[i];
        ps.x += v.x; ps.y += v.y; ps.z += v.z; ps.w += v.w;
        pq.x = fmaf(v.x, v.x, pq.x);
        pq.y = fmaf(v.y, v.y, pq.y);
        pq.z = fmaf(v.z, v.z, pq.z);
        pq.w = fmaf(v.w, v.w, pq.w);
    }
    __shared__ float4 sS[256];
    __shared__ float4 sQ[256];
    sS[threadIdx.x] = ps;
    sQ[threadIdx.x] = pq;
    __syncthreads();
    if (threadIdx.x < 16) {
        const int c = threadIdx.x;      // feature quad class
        float4 a = sS[c], b = sQ[c];
        for (int u = 1; u < 16; ++u) {
            a = f4add(a, sS[c + u * 16]);
            b = f4add(b, sQ[c + u * 16]);
        }
        atomicAdd(&stats[c * 4 + 0], a.x);
        atomicAdd(&stats[c * 4 + 1], a.y);
        atomicAdd(&stats[c * 4 + 2], a.z);
        atomicAdd(&stats[c * 4 + 3], a.w);
        atomicAdd(&stats[64 + c * 4 + 0], b.x);
        atomicAdd(&stats[64 + c * 4 + 1], b.y);
        atomicAdd(&stats[64 + c * 4 + 2], b.z);
        atomicAdd(&stats[64 + c * 4 + 3], b.w);
    }
}

// ---------------- Kernel C2: BN finalize + normalize in place (float4) --------
__global__ __launch_bounds__(256) void bn_normalize_kernel(
    float4* __restrict__ h,
    const float* __restrict__ stats,
    const float* __restrict__ gamma,
    const float* __restrict__ beta,
    int nNodes)
{
    __shared__ float sscale[F];
    __shared__ float sshift[F];
    if (threadIdx.x < F) {
        const int f = threadIdx.x;
        const float invN = 1.0f / (float)nNodes;
        const float mean = stats[f] * invN;
        const float var  = stats[F + f] * invN - mean * mean;
        const float inv  = rsqrtf(var + BN_EPS);
        const float g    = gamma[f];
        sscale[f] = inv * g;
        sshift[f] = beta[f] - mean * inv * g;
    }
    __syncthreads();

    const int total4 = nNodes * (F / 4);
    const int stride = gridDim.x * blockDim.x;
    for (int i = blockIdx.x * blockDim.x + threadIdx.x; i < total4; i += stride) {
        const int f0 = (i & 15) * 4;
        float4 v = h[i];
        v.x = fmaf(v.x, sscale[f0 + 0], sshift[f0 + 0]);
        v.y = fmaf(v.y, sscale[f0 + 1], sshift[f0 + 1]);
        v.z = fmaf(v.z, sscale[f0 + 2], sshift[f0 + 2]);
        v.w = fmaf(v.w, sscale[f0 + 3], sshift[f0 + 3]);
        h[i] = v;
    }
}

extern "C" void kernel_launch(void* const* d_in, const int* in_sizes, int n_in,
                              void* d_out, int out_size, void* d_ws, size_t ws_size,
                              hipStream_t stream)
{
    const float* x     = (const float*)d_in[0];
    const int*   eidx  = (const int*)d_in[1];   // [2, E]: row then col
    const float* W1    = (const float*)d_in[2];
    const float* b1    = (const float*)d_in[3];
    const float* W2    = (const float*)d_in[4];
    const float* b2    = (const float*)d_in[5];
    const float* gamma = (const float*)d_in[6];
    const float* beta  = (const float*)d_in[7];

    const int nNodes = in_sizes[0] / F;
    const int nEdges = in_sizes[1] / 2;
    const int* row = eidx;
    const int* col = eidx + nEdges;

    // workspace layout (4-byte elems): counts|stats contiguous for one memset
    char* wsp = (char*)d_ws;
    int*   counts     = (int*)wsp;                    wsp += (size_t)nNodes * 4;
    float* stats      = (float*)wsp;                  wsp += 128 * 4;
    int*   starts     = (int*)wsp;                    wsp += (size_t)(nNodes + 1) * 4;
    int*   blocksums  = (int*)wsp;                    wsp += 512 * 4;
    int*   rank       = (int*)wsp;                    wsp += (size_t)nEdges * 4;
    int*   col_sorted = (int*)wsp;                    wsp += (size_t)(nEdges + 16) * 4;
    float* hbuf = (float*)d_out;   // serves as agg, then h2, then final out

    const int nblocks_scan = (nNodes + 255) / 256;

    hipMemsetAsync(counts, 0, (size_t)nNodes * 4 + 128 * 4, stream);

    hist_kernel<<<2048, 256, 0, stream>>>(row, col, counts, rank, nEdges);
    scan1_kernel<<<nblocks_scan, 256, 0, stream>>>(counts, starts, blocksums, nNodes);
    scan2_kernel<<<1, 512, 0, stream>>>(blocksums, starts, nblocks_scan, nNodes);
    scan3_kernel<<<nblocks_scan, 256, 0, stream>>>(starts, blocksums, nNodes);
    reorder_kernel<<<2048, 256, 0, stream>>>(row, col, starts, rank, col_sorted, nEdges);

    // A: one wave per node
    gather_kernel<<<(nNodes + 3) / 4, 256, 0, stream>>>(
        (const float4*)x, starts, col_sorted, (float4*)hbuf, nNodes);

    // B: 64 nodes per block, 4 waves split over output features
    mlp_kernel<<<(nNodes + 63) / 64, 256, 0, stream>>>(
        hbuf, W1, b1, W2, b2, hbuf, nNodes);

    stats_kernel<<<512, 256, 0, stream>>>((const float4*)hbuf, stats, nNodes * (F / 4));
    bn_normalize_kernel<<<2048, 256, 0, stream>>>((float4*)hbuf, stats, gamma, beta, nNodes);
}

// Round 9
// 301.050 us; speedup vs baseline: 1.1097x; 1.1097x over previous
//
#include <hip/hip_runtime.h>

#define F 64
#define BN_EPS 1e-5f

static __device__ __forceinline__ float4 f4add(float4 a, float4 b) {
    a.x += b.x; a.y += b.y; a.z += b.z; a.w += b.w; return a;
}

// ---------------- Kernel 1: degree histogram + per-edge rank ----------------
__global__ __launch_bounds__(256) void hist_kernel(
    const int* __restrict__ row,
    const int* __restrict__ col,
    int* __restrict__ counts,   // [N], pre-zeroed
    int* __restrict__ rank,     // [E], coalesced write
    int nEdges)
{
    const int stride = gridDim.x * blockDim.x;
    for (int e = blockIdx.x * blockDim.x + threadIdx.x; e < nEdges; e += stride) {
        const int r = row[e];
        const int c = col[e];
        if (r != c) {
            rank[e] = atomicAdd(&counts[r], 1);
        }
    }
}

// ---------------- Kernel 2a: per-block scan of counts ----------------
__global__ __launch_bounds__(256) void scan1_kernel(
    const int* __restrict__ counts,
    int* __restrict__ starts,       // [N+1]
    int* __restrict__ blocksums,    // [nblocks]
    int n)
{
    __shared__ int tmp[256];
    const int t = threadIdx.x;
    const int i = blockIdx.x * 256 + t;
    const int v = (i < n) ? counts[i] : 0;
    tmp[t] = v;
    __syncthreads();
    for (int off = 1; off < 256; off <<= 1) {
        const int a = (t >= off) ? tmp[t - off] : 0;
        __syncthreads();
        tmp[t] += a;
        __syncthreads();
    }
    if (i < n) starts[i] = tmp[t] - v;     // exclusive within block
    if (t == 255) blocksums[blockIdx.x] = tmp[255];
}

// ---------------- Kernel 2b: scan of block sums (single block) ----------------
__global__ __launch_bounds__(512) void scan2_kernel(
    int* __restrict__ blocksums,
    int* __restrict__ starts,
    int nblocks, int n)
{
    __shared__ int tmp[512];
    const int t = threadIdx.x;
    const int v = (t < nblocks) ? blocksums[t] : 0;
    tmp[t] = v;
    __syncthreads();
    for (int off = 1; off < 512; off <<= 1) {
        const int a = (t >= off) ? tmp[t - off] : 0;
        __syncthreads();
        tmp[t] += a;
        __syncthreads();
    }
    if (t < nblocks) blocksums[t] = tmp[t] - v;   // exclusive
    if (t == 511) starts[n] = tmp[511];           // total kept-edge count
}

// ---------------- Kernel 2c: add block offsets ----------------
__global__ __launch_bounds__(256) void scan3_kernel(
    int* __restrict__ starts,
    const int* __restrict__ blocksums,
    int n)
{
    const int i = blockIdx.x * 256 + threadIdx.x;
    if (i < n) starts[i] += blocksums[i >> 8];
}

// ---------------- Kernel 3: reorder cols into CSR order (no atomics) ----------
__global__ __launch_bounds__(256) void reorder_kernel(
    const int* __restrict__ row,
    const int* __restrict__ col,
    const int* __restrict__ starts,
    const int* __restrict__ rank,
    int* __restrict__ col_sorted,
    int nEdges)
{
    const int stride = gridDim.x * blockDim.x;
    for (int e = blockIdx.x * blockDim.x + threadIdx.x; e < nEdges; e += stride) {
        const int r = row[e];
        const int c = col[e];
        if (r != c) {
            col_sorted[starts[r] + rank[e]] = c;   // fire-and-forget scatter
        }
    }
}

// ---------------- Kernel A: gather-aggregate (float4, direct index loads) -----
__global__ __launch_bounds__(256) void gather_kernel(
    const float4* __restrict__ x4,
    const int* __restrict__ starts,
    const int* __restrict__ col_sorted,
    float4* __restrict__ agg4,     // = d_out viewed as float4
    int nNodes)
{
    const int lane = threadIdx.x & 63;
    const int w = threadIdx.x >> 6;
    const int r = blockIdx.x * 4 + w;
    if (r >= nNodes) return;

    const int g = lane >> 4;   // 0..3
    const int q = lane & 15;   // 0..15

    const int s  = starts[r];
    const int en = starts[r + 1];

    const float4 vself = x4[(size_t)r * 16 + q];

    float4 a0 = {0,0,0,0}, a1 = {0,0,0,0}, a2 = {0,0,0,0}, a3 = {0,0,0,0};

    int e = s;
    for (; e + 16 <= en; e += 16) {
        const int c0 = col_sorted[e + g];
        const int c1 = col_sorted[e + 4 + g];
        const int c2 = col_sorted[e + 8 + g];
        const int c3 = col_sorted[e + 12 + g];
        const float4 t0 = x4[(size_t)c0 * 16 + q];
        const float4 t1 = x4[(size_t)c1 * 16 + q];
        const float4 t2 = x4[(size_t)c2 * 16 + q];
        const float4 t3 = x4[(size_t)c3 * 16 + q];
        a0 = f4add(a0, t0);
        a1 = f4add(a1, t1);
        a2 = f4add(a2, t2);
        a3 = f4add(a3, t3);
    }
    for (; e + 4 <= en; e += 4) {
        const int c = col_sorted[e + g];
        a0 = f4add(a0, x4[(size_t)c * 16 + q]);
    }
    if (e + g < en) {
        const int c = col_sorted[e + g];
        a1 = f4add(a1, x4[(size_t)c * 16 + q]);
    }

    float4 v = f4add(f4add(a0, a1), f4add(a2, a3));
    v.x += __shfl_xor(v.x, 16, 64);
    v.y += __shfl_xor(v.y, 16, 64);
    v.z += __shfl_xor(v.z, 16, 64);
    v.w += __shfl_xor(v.w, 16, 64);
    v.x += __shfl_xor(v.x, 32, 64);
    v.y += __shfl_xor(v.y, 32, 64);
    v.z += __shfl_xor(v.z, 32, 64);
    v.w += __shfl_xor(v.w, 32, 64);
    v = f4add(v, vself);

    if (g == 0) {
        agg4[(size_t)r * 16 + q] = v;
    }
}

// ---------------- Kernel B: MLP, 128-node tile / 128 threads ------------------
// thread = node. Input staged transposed once (sIn, padded, barrier-protected).
// h1 lives in column-private LDS (sH, row-reads conflict-free, NO barrier needed
// since column t is only ever touched by thread t). k-loops fully unrolled so
// every weight s_load is base+immediate -> deep scalar prefetch pipeline.
// acc[16] chunking caps VGPR (~50) so spilling is impossible. Output bounced
// through sIn (reused) for a fully-linear coalesced float4 store pass.
__global__ __launch_bounds__(128) void mlp_kernel(
    const float* in_,               // = d_out (agg) — same buffer as out_
    const float* __restrict__ W1,
    const float* __restrict__ b1,
    const float* __restrict__ W2,
    const float* __restrict__ b2,
    float* out_,                    // = d_out (h2)
    int nNodes)
{
    __shared__ float sIn[64][129];  // 33 KB, transposed [feat][node]; reused for h2
    __shared__ float sH[64][128];   // 32 KB, h1 [feat][node] — column-private

    const int t  = threadIdx.x;     // 0..127 = node-within-tile
    const int t0 = blockIdx.x * 128;
    const float4* in4 = (const float4*)in_;

    // ---- stage 128 nodes x 64 feats, transposed, coalesced ----
    #pragma unroll
    for (int i = 0; i < 16; ++i) {
        const int flat = i * 128 + t;       // 0..2047
        const int node = flat >> 4;         // 0..127
        const int quad = flat & 15;         // 0..15
        int nn = t0 + node;
        if (nn >= nNodes) nn = nNodes - 1;  // clamp (dup, discarded at store)
        const float4 vv = in4[(size_t)nn * 16 + quad];
        sIn[quad * 4 + 0][node] = vv.x;
        sIn[quad * 4 + 1][node] = vv.y;
        sIn[quad * 4 + 2][node] = vv.z;
        sIn[quad * 4 + 3][node] = vv.w;
    }
    __syncthreads();

    // ---- layer 1: 4 output chunks of 16; k fully unrolled ----
    for (int oc = 0; oc < 4; ++oc) {
        float acc[16];
        #pragma unroll
        for (int j = 0; j < 16; ++j) acc[j] = b1[oc * 16 + j];
        #pragma unroll
        for (int k = 0; k < 64; ++k) {
            const float vk = sIn[k][t];
            const float* wr = &W1[k * 64 + oc * 16];     // uniform, imm-offset s_load
            #pragma unroll
            for (int j = 0; j < 16; ++j) acc[j] = fmaf(vk, wr[j], acc[j]);
        }
        #pragma unroll
        for (int j = 0; j < 16; ++j) sH[oc * 16 + j][t] = fmaxf(acc[j], 0.0f);
    }
    // no barrier: sH column t written and read only by thread t

    // ---- layer 2: 4 output chunks of 16; k fully unrolled ----
    for (int oc = 0; oc < 4; ++oc) {
        float acc[16];
        #pragma unroll
        for (int j = 0; j < 16; ++j) acc[j] = b2[oc * 16 + j];
        #pragma unroll
        for (int k = 0; k < 64; ++k) {
            const float hk = sH[k][t];
            const float* wr = &W2[k * 64 + oc * 16];     // uniform, imm-offset s_load
            #pragma unroll
            for (int j = 0; j < 16; ++j) acc[j] = fmaf(hk, wr[j], acc[j]);
        }
        #pragma unroll
        for (int j = 0; j < 16; ++j) sIn[oc * 16 + j][t] = fmaxf(acc[j], 0.0f);
    }
    __syncthreads();   // h2 tile complete; cross-thread store pass follows

    // ---- fully-linear coalesced store ----
    float4* out4 = (float4*)out_;
    const int lim4 = nNodes * 16;
    #pragma unroll
    for (int i = 0; i < 16; ++i) {
        const int flat = i * 128 + t;       // 0..2047
        const int node = flat >> 4;
        const int quad = flat & 15;
        const int g4 = t0 * 16 + flat;      // linear in flat -> perfect coalescing
        if (g4 < lim4) {
            float4 vv;
            vv.x = sIn[quad * 4 + 0][node];
            vv.y = sIn[quad * 4 + 1][node];
            vv.z = sIn[quad * 4 + 2][node];
            vv.w = sIn[quad * 4 + 3][node];
            out4[g4] = vv;
        }
    }
}

// ---------------- Kernel C1: BN stats (sum / sumsq per feature) ---------------
__global__ __launch_bounds__(256) void stats_kernel(
    const float4* __restrict__ h,
    float* __restrict__ stats,      // [0..63]=sum, [64..127]=sumsq, pre-zeroed
    int total4)
{
    float4 ps = {0,0,0,0}, pq = {0,0,0,0};
    const int stride = gridDim.x * blockDim.x;   // multiple of 16
    for (int i = blockIdx.x * blockDim.x + threadIdx.x; i < total4; i += stride) {
        const float4 v = h[i];
        ps.x += v.x; ps.y += v.y; ps.z += v.z; ps.w += v.w;
        pq.x = fmaf(v.x, v.x, pq.x);
        pq.y = fmaf(v.y, v.y, pq.y);
        pq.z = fmaf(v.z, v.z, pq.z);
        pq.w = fmaf(v.w, v.w, pq.w);
    }
    __shared__ float4 sS[256];
    __shared__ float4 sQ[256];
    sS[threadIdx.x] = ps;
    sQ[threadIdx.x] = pq;
    __syncthreads();
    if (threadIdx.x < 16) {
        const int c = threadIdx.x;      // feature quad class
        float4 a = sS[c], b = sQ[c];
        for (int u = 1; u < 16; ++u) {
            a = f4add(a, sS[c + u * 16]);
            b = f4add(b, sQ[c + u * 16]);
        }
        atomicAdd(&stats[c * 4 + 0], a.x);
        atomicAdd(&stats[c * 4 + 1], a.y);
        atomicAdd(&stats[c * 4 + 2], a.z);
        atomicAdd(&stats[c * 4 + 3], a.w);
        atomicAdd(&stats[64 + c * 4 + 0], b.x);
        atomicAdd(&stats[64 + c * 4 + 1], b.y);
        atomicAdd(&stats[64 + c * 4 + 2], b.z);
        atomicAdd(&stats[64 + c * 4 + 3], b.w);
    }
}

// ---------------- Kernel C2: BN finalize + normalize in place (float4) --------
__global__ __launch_bounds__(256) void bn_normalize_kernel(
    float4* __restrict__ h,
    const float* __restrict__ stats,
    const float* __restrict__ gamma,
    const float* __restrict__ beta,
    int nNodes)
{
    __shared__ float sscale[F];
    __shared__ float sshift[F];
    if (threadIdx.x < F) {
        const int f = threadIdx.x;
        const float invN = 1.0f / (float)nNodes;
        const float mean = stats[f] * invN;
        const float var  = stats[F + f] * invN - mean * mean;
        const float inv  = rsqrtf(var + BN_EPS);
        const float g    = gamma[f];
        sscale[f] = inv * g;
        sshift[f] = beta[f] - mean * inv * g;
    }
    __syncthreads();

    const int total4 = nNodes * (F / 4);
    const int stride = gridDim.x * blockDim.x;
    for (int i = blockIdx.x * blockDim.x + threadIdx.x; i < total4; i += stride) {
        const int f0 = (i & 15) * 4;
        float4 v = h[i];
        v.x = fmaf(v.x, sscale[f0 + 0], sshift[f0 + 0]);
        v.y = fmaf(v.y, sscale[f0 + 1], sshift[f0 + 1]);
        v.z = fmaf(v.z, sscale[f0 + 2], sshift[f0 + 2]);
        v.w = fmaf(v.w, sscale[f0 + 3], sshift[f0 + 3]);
        h[i] = v;
    }
}

extern "C" void kernel_launch(void* const* d_in, const int* in_sizes, int n_in,
                              void* d_out, int out_size, void* d_ws, size_t ws_size,
                              hipStream_t stream)
{
    const float* x     = (const float*)d_in[0];
    const int*   eidx  = (const int*)d_in[1];   // [2, E]: row then col
    const float* W1    = (const float*)d_in[2];
    const float* b1    = (const float*)d_in[3];
    const float* W2    = (const float*)d_in[4];
    const float* b2    = (const float*)d_in[5];
    const float* gamma = (const float*)d_in[6];
    const float* beta  = (const float*)d_in[7];

    const int nNodes = in_sizes[0] / F;
    const int nEdges = in_sizes[1] / 2;
    const int* row = eidx;
    const int* col = eidx + nEdges;

    // workspace layout (4-byte elems): counts|stats contiguous for one memset
    char* wsp = (char*)d_ws;
    int*   counts     = (int*)wsp;                    wsp += (size_t)nNodes * 4;
    float* stats      = (float*)wsp;                  wsp += 128 * 4;
    int*   starts     = (int*)wsp;                    wsp += (size_t)(nNodes + 1) * 4;
    int*   blocksums  = (int*)wsp;                    wsp += 512 * 4;
    int*   rank       = (int*)wsp;                    wsp += (size_t)nEdges * 4;
    int*   col_sorted = (int*)wsp;                    wsp += (size_t)(nEdges + 16) * 4;
    float* hbuf = (float*)d_out;   // serves as agg, then h2, then final out

    const int nblocks_scan = (nNodes + 255) / 256;

    hipMemsetAsync(counts, 0, (size_t)nNodes * 4 + 128 * 4, stream);

    hist_kernel<<<2048, 256, 0, stream>>>(row, col, counts, rank, nEdges);
    scan1_kernel<<<nblocks_scan, 256, 0, stream>>>(counts, starts, blocksums, nNodes);
    scan2_kernel<<<1, 512, 0, stream>>>(blocksums, starts, nblocks_scan, nNodes);
    scan3_kernel<<<nblocks_scan, 256, 0, stream>>>(starts, blocksums, nNodes);
    reorder_kernel<<<2048, 256, 0, stream>>>(row, col, starts, rank, col_sorted, nEdges);

    // A: one wave per node
    gather_kernel<<<(nNodes + 3) / 4, 256, 0, stream>>>(
        (const float4*)x, starts, col_sorted, (float4*)hbuf, nNodes);

    // B: 128 nodes per 128-thread block
    mlp_kernel<<<(nNodes + 127) / 128, 128, 0, stream>>>(
        hbuf, W1, b1, W2, b2, hbuf, nNodes);

    stats_kernel<<<512, 256, 0, stream>>>((const float4*)hbuf, stats, nNodes * (F / 4));
    bn_normalize_kernel<<<2048, 256, 0, stream>>>((float4*)hbuf, stats, gamma, beta, nNodes);
}

// Round 10
// 243.145 us; speedup vs baseline: 1.3740x; 1.2381x over previous
//
#include <hip/hip_runtime.h>

#define F 64
#define BN_EPS 1e-5f

typedef __attribute__((ext_vector_type(8))) short bf16x8;
typedef __attribute__((ext_vector_type(4))) float f32x4;

static __device__ __forceinline__ float4 f4add(float4 a, float4 b) {
    a.x += b.x; a.y += b.y; a.z += b.z; a.w += b.w; return a;
}

// f32 -> bf16 with round-to-nearest-even
static __device__ __forceinline__ short f2bf(float x) {
    union { float f; unsigned u; } v; v.f = x;
    const unsigned r = (v.u + 0x7fffu + ((v.u >> 16) & 1u)) >> 16;
    return (short)r;
}

// ---------------- Kernel 1: degree histogram + per-edge rank ----------------
__global__ __launch_bounds__(256) void hist_kernel(
    const int* __restrict__ row,
    const int* __restrict__ col,
    int* __restrict__ counts,   // [N], pre-zeroed
    int* __restrict__ rank,     // [E], coalesced write
    int nEdges)
{
    const int stride = gridDim.x * blockDim.x;
    for (int e = blockIdx.x * blockDim.x + threadIdx.x; e < nEdges; e += stride) {
        const int r = row[e];
        const int c = col[e];
        if (r != c) {
            rank[e] = atomicAdd(&counts[r], 1);
        }
    }
}

// ---------------- Kernel 2a: per-block scan of counts ----------------
__global__ __launch_bounds__(256) void scan1_kernel(
    const int* __restrict__ counts,
    int* __restrict__ starts,       // [N+1]
    int* __restrict__ blocksums,    // [nblocks]
    int n)
{
    __shared__ int tmp[256];
    const int t = threadIdx.x;
    const int i = blockIdx.x * 256 + t;
    const int v = (i < n) ? counts[i] : 0;
    tmp[t] = v;
    __syncthreads();
    for (int off = 1; off < 256; off <<= 1) {
        const int a = (t >= off) ? tmp[t - off] : 0;
        __syncthreads();
        tmp[t] += a;
        __syncthreads();
    }
    if (i < n) starts[i] = tmp[t] - v;     // exclusive within block
    if (t == 255) blocksums[blockIdx.x] = tmp[255];
}

// ---------------- Kernel 2b: scan of block sums (single block) ----------------
__global__ __launch_bounds__(512) void scan2_kernel(
    int* __restrict__ blocksums,
    int* __restrict__ starts,
    int nblocks, int n)
{
    __shared__ int tmp[512];
    const int t = threadIdx.x;
    const int v = (t < nblocks) ? blocksums[t] : 0;
    tmp[t] = v;
    __syncthreads();
    for (int off = 1; off < 512; off <<= 1) {
        const int a = (t >= off) ? tmp[t - off] : 0;
        __syncthreads();
        tmp[t] += a;
        __syncthreads();
    }
    if (t < nblocks) blocksums[t] = tmp[t] - v;   // exclusive
    if (t == 511) starts[n] = tmp[511];           // total kept-edge count
}

// ---------------- Kernel 2c: add block offsets ----------------
__global__ __launch_bounds__(256) void scan3_kernel(
    int* __restrict__ starts,
    const int* __restrict__ blocksums,
    int n)
{
    const int i = blockIdx.x * 256 + threadIdx.x;
    if (i < n) starts[i] += blocksums[i >> 8];
}

// ---------------- Kernel 3: reorder cols into CSR order (no atomics) ----------
__global__ __launch_bounds__(256) void reorder_kernel(
    const int* __restrict__ row,
    const int* __restrict__ col,
    const int* __restrict__ starts,
    const int* __restrict__ rank,
    int* __restrict__ col_sorted,
    int nEdges)
{
    const int stride = gridDim.x * blockDim.x;
    for (int e = blockIdx.x * blockDim.x + threadIdx.x; e < nEdges; e += stride) {
        const int r = row[e];
        const int c = col[e];
        if (r != c) {
            col_sorted[starts[r] + rank[e]] = c;   // fire-and-forget scatter
        }
    }
}

// ---------------- Kernel A: gather-aggregate (float4, direct index loads) -----
__global__ __launch_bounds__(256) void gather_kernel(
    const float4* __restrict__ x4,
    const int* __restrict__ starts,
    const int* __restrict__ col_sorted,
    float4* __restrict__ agg4,     // = d_out viewed as float4
    int nNodes)
{
    const int lane = threadIdx.x & 63;
    const int w = threadIdx.x >> 6;
    const int r = blockIdx.x * 4 + w;
    if (r >= nNodes) return;

    const int g = lane >> 4;   // 0..3
    const int q = lane & 15;   // 0..15

    const int s  = starts[r];
    const int en = starts[r + 1];

    const float4 vself = x4[(size_t)r * 16 + q];

    float4 a0 = {0,0,0,0}, a1 = {0,0,0,0}, a2 = {0,0,0,0}, a3 = {0,0,0,0};

    int e = s;
    for (; e + 16 <= en; e += 16) {
        const int c0 = col_sorted[e + g];
        const int c1 = col_sorted[e + 4 + g];
        const int c2 = col_sorted[e + 8 + g];
        const int c3 = col_sorted[e + 12 + g];
        const float4 t0 = x4[(size_t)c0 * 16 + q];
        const float4 t1 = x4[(size_t)c1 * 16 + q];
        const float4 t2 = x4[(size_t)c2 * 16 + q];
        const float4 t3 = x4[(size_t)c3 * 16 + q];
        a0 = f4add(a0, t0);
        a1 = f4add(a1, t1);
        a2 = f4add(a2, t2);
        a3 = f4add(a3, t3);
    }
    for (; e + 4 <= en; e += 4) {
        const int c = col_sorted[e + g];
        a0 = f4add(a0, x4[(size_t)c * 16 + q]);
    }
    if (e + g < en) {
        const int c = col_sorted[e + g];
        a1 = f4add(a1, x4[(size_t)c * 16 + q]);
    }

    float4 v = f4add(f4add(a0, a1), f4add(a2, a3));
    v.x += __shfl_xor(v.x, 16, 64);
    v.y += __shfl_xor(v.y, 16, 64);
    v.z += __shfl_xor(v.z, 16, 64);
    v.w += __shfl_xor(v.w, 16, 64);
    v.x += __shfl_xor(v.x, 32, 64);
    v.y += __shfl_xor(v.y, 32, 64);
    v.z += __shfl_xor(v.z, 32, 64);
    v.w += __shfl_xor(v.w, 32, 64);
    v = f4add(v, vself);

    if (g == 0) {
        agg4[(size_t)r * 16 + q] = v;
    }
}

// ---------------- Kernel B: MFMA bf16 MLP (64 nodes/block, 16/wave) -----------
// Per wave: 16-node tile. Layer l: D[16 nodes x 16 feats] per n-chunk via
// mfma_f32_16x16x32_bf16, K=64 in 2 steps. Frag layouts (guide-verified):
//   A/B operand: lane holds [row = lane&15][k = (lane>>4)*8 + e]
//   C/D:         col = lane&15, row = (lane>>4)*4 + reg
// Semantics D = X * Y^T: first operand rows = nodes, second = W^T rows
//   -> second-operand frag element e = W[k][n] with n = lane&15.
// h1 crosses lane-distribution via padded per-wave LDS + block barrier.
__global__ __launch_bounds__(256) void mlp_kernel(
    const float* in_,               // = d_out (agg) — same buffer as out_
    const float* __restrict__ W1,
    const float* __restrict__ b1,
    const float* __restrict__ W2,
    const float* __restrict__ b2,
    float* out_,                    // = d_out (h2)
    int nNodes)
{
    __shared__ float sH[4][16][68];   // per-wave h1 [node][feat], +4 pad (16B-aligned rows)

    const int tid  = threadIdx.x;
    const int lane = tid & 63;
    const int w    = tid >> 6;
    const int nb   = lane & 15;       // feat-in-chunk / node-row selector
    const int kg   = lane >> 4;       // k-group 0..3
    const int kb   = kg * 8;          // k base within 32-wide step

    // ---- weight fragments: w{1,2}f[s][c], element e = W[s*32+kb+e][c*16+nb] ----
    bf16x8 w1f[2][4], w2f[2][4];
    #pragma unroll
    for (int s = 0; s < 2; ++s) {
        #pragma unroll
        for (int c = 0; c < 4; ++c) {
            #pragma unroll
            for (int e = 0; e < 8; ++e) {
                const int k = s * 32 + kb + e;
                w1f[s][c][e] = f2bf(W1[k * 64 + c * 16 + nb]);
                w2f[s][c][e] = f2bf(W2[k * 64 + c * 16 + nb]);
            }
        }
    }

    const int node0 = blockIdx.x * 64 + w * 16;

    // ---- A fragment: lane row = node0+nb, k = s*32+kb+e ----
    int an = node0 + nb;
    if (an >= nNodes) an = nNodes - 1;      // clamp: stays inside this block's tile
    const float* arow = in_ + (size_t)an * 64;
    bf16x8 a[2];
    #pragma unroll
    for (int s = 0; s < 2; ++s)
        #pragma unroll
        for (int e = 0; e < 8; ++e)
            a[s][e] = f2bf(arow[s * 32 + kb + e]);

    // ---- layer 1 -> ReLU -> per-wave LDS tile ----
    #pragma unroll
    for (int c = 0; c < 4; ++c) {
        const float bias = b1[c * 16 + nb];
        f32x4 acc = {bias, bias, bias, bias};
        acc = __builtin_amdgcn_mfma_f32_16x16x32_bf16(a[0], w1f[0][c], acc, 0, 0, 0);
        acc = __builtin_amdgcn_mfma_f32_16x16x32_bf16(a[1], w1f[1][c], acc, 0, 0, 0);
        #pragma unroll
        for (int r = 0; r < 4; ++r)
            sH[w][kg * 4 + r][c * 16 + nb] = fmaxf(acc[r], 0.0f);
    }
    __syncthreads();   // make h1 visible across lanes (rule: no barrier-free LDS)

    // ---- h1 -> A2 fragment: lane row = node nb, k = s*32+kb+e ----
    bf16x8 h[2];
    #pragma unroll
    for (int s = 0; s < 2; ++s)
        #pragma unroll
        for (int e = 0; e < 8; ++e)
            h[s][e] = f2bf(sH[w][nb][s * 32 + kb + e]);

    // ---- layer 2 -> ReLU -> store (lanes 0-15 = 64B contiguous per node) ----
    #pragma unroll
    for (int c = 0; c < 4; ++c) {
        const float bias = b2[c * 16 + nb];
        f32x4 acc = {bias, bias, bias, bias};
        acc = __builtin_amdgcn_mfma_f32_16x16x32_bf16(h[0], w2f[0][c], acc, 0, 0, 0);
        acc = __builtin_amdgcn_mfma_f32_16x16x32_bf16(h[1], w2f[1][c], acc, 0, 0, 0);
        #pragma unroll
        for (int r = 0; r < 4; ++r) {
            const int node = node0 + kg * 4 + r;
            if (node < nNodes)
                out_[(size_t)node * 64 + c * 16 + nb] = fmaxf(acc[r], 0.0f);
        }
    }
}

// ---------------- Kernel C1: BN stats (sum / sumsq per feature) ---------------
__global__ __launch_bounds__(256) void stats_kernel(
    const float4* __restrict__ h,
    float* __restrict__ stats,      // [0..63]=sum, [64..127]=sumsq, pre-zeroed
    int total4)
{
    float4 ps = {0,0,0,0}, pq = {0,0,0,0};
    const int stride = gridDim.x * blockDim.x;   // multiple of 16
    for (int i = blockIdx.x * blockDim.x + threadIdx.x; i < total4; i += stride) {
        const float4 v = h[i];
        ps.x += v.x; ps.y += v.y; ps.z += v.z; ps.w += v.w;
        pq.x = fmaf(v.x, v.x, pq.x);
        pq.y = fmaf(v.y, v.y, pq.y);
        pq.z = fmaf(v.z, v.z, pq.z);
        pq.w = fmaf(v.w, v.w, pq.w);
    }
    __shared__ float4 sS[256];
    __shared__ float4 sQ[256];
    sS[threadIdx.x] = ps;
    sQ[threadIdx.x] = pq;
    __syncthreads();
    if (threadIdx.x < 16) {
        const int c = threadIdx.x;      // feature quad class
        float4 a = sS[c], b = sQ[c];
        for (int u = 1; u < 16; ++u) {
            a = f4add(a, sS[c + u * 16]);
            b = f4add(b, sQ[c + u * 16]);
        }
        atomicAdd(&stats[c * 4 + 0], a.x);
        atomicAdd(&stats[c * 4 + 1], a.y);
        atomicAdd(&stats[c * 4 + 2], a.z);
        atomicAdd(&stats[c * 4 + 3], a.w);
        atomicAdd(&stats[64 + c * 4 + 0], b.x);
        atomicAdd(&stats[64 + c * 4 + 1], b.y);
        atomicAdd(&stats[64 + c * 4 + 2], b.z);
        atomicAdd(&stats[64 + c * 4 + 3], b.w);
    }
}

// ---------------- Kernel C2: BN finalize + normalize in place (float4) --------
__global__ __launch_bounds__(256) void bn_normalize_kernel(
    float4* __restrict__ h,
    const float* __restrict__ stats,
    const float* __restrict__ gamma,
    const float* __restrict__ beta,
    int nNodes)
{
    __shared__ float sscale[F];
    __shared__ float sshift[F];
    if (threadIdx.x < F) {
        const int f = threadIdx.x;
        const float invN = 1.0f / (float)nNodes;
        const float mean = stats[f] * invN;
        const float var  = stats[F + f] * invN - mean * mean;
        const float inv  = rsqrtf(var + BN_EPS);
        const float g    = gamma[f];
        sscale[f] = inv * g;
        sshift[f] = beta[f] - mean * inv * g;
    }
    __syncthreads();

    const int total4 = nNodes * (F / 4);
    const int stride = gridDim.x * blockDim.x;
    for (int i = blockIdx.x * blockDim.x + threadIdx.x; i < total4; i += stride) {
        const int f0 = (i & 15) * 4;
        float4 v = h[i];
        v.x = fmaf(v.x, sscale[f0 + 0], sshift[f0 + 0]);
        v.y = fmaf(v.y, sscale[f0 + 1], sshift[f0 + 1]);
        v.z = fmaf(v.z, sscale[f0 + 2], sshift[f0 + 2]);
        v.w = fmaf(v.w, sscale[f0 + 3], sshift[f0 + 3]);
        h[i] = v;
    }
}

extern "C" void kernel_launch(void* const* d_in, const int* in_sizes, int n_in,
                              void* d_out, int out_size, void* d_ws, size_t ws_size,
                              hipStream_t stream)
{
    const float* x     = (const float*)d_in[0];
    const int*   eidx  = (const int*)d_in[1];   // [2, E]: row then col
    const float* W1    = (const float*)d_in[2];
    const float* b1    = (const float*)d_in[3];
    const float* W2    = (const float*)d_in[4];
    const float* b2    = (const float*)d_in[5];
    const float* gamma = (const float*)d_in[6];
    const float* beta  = (const float*)d_in[7];

    const int nNodes = in_sizes[0] / F;
    const int nEdges = in_sizes[1] / 2;
    const int* row = eidx;
    const int* col = eidx + nEdges;

    // workspace layout (4-byte elems): counts|stats contiguous for one memset
    char* wsp = (char*)d_ws;
    int*   counts     = (int*)wsp;                    wsp += (size_t)nNodes * 4;
    float* stats      = (float*)wsp;                  wsp += 128 * 4;
    int*   starts     = (int*)wsp;                    wsp += (size_t)(nNodes + 1) * 4;
    int*   blocksums  = (int*)wsp;                    wsp += 512 * 4;
    int*   rank       = (int*)wsp;                    wsp += (size_t)nEdges * 4;
    int*   col_sorted = (int*)wsp;                    wsp += (size_t)(nEdges + 16) * 4;
    float* hbuf = (float*)d_out;   // serves as agg, then h2, then final out

    const int nblocks_scan = (nNodes + 255) / 256;

    hipMemsetAsync(counts, 0, (size_t)nNodes * 4 + 128 * 4, stream);

    hist_kernel<<<2048, 256, 0, stream>>>(row, col, counts, rank, nEdges);
    scan1_kernel<<<nblocks_scan, 256, 0, stream>>>(counts, starts, blocksums, nNodes);
    scan2_kernel<<<1, 512, 0, stream>>>(blocksums, starts, nblocks_scan, nNodes);
    scan3_kernel<<<nblocks_scan, 256, 0, stream>>>(starts, blocksums, nNodes);
    reorder_kernel<<<2048, 256, 0, stream>>>(row, col, starts, rank, col_sorted, nEdges);

    // A: one wave per node
    gather_kernel<<<(nNodes + 3) / 4, 256, 0, stream>>>(
        (const float4*)x, starts, col_sorted, (float4*)hbuf, nNodes);

    // B: MFMA MLP, 64 nodes per 256-thread block (16 per wave)
    mlp_kernel<<<(nNodes + 63) / 64, 256, 0, stream>>>(
        hbuf, W1, b1, W2, b2, hbuf, nNodes);

    stats_kernel<<<512, 256, 0, stream>>>((const float4*)hbuf, stats, nNodes * (F / 4));
    bn_normalize_kernel<<<2048, 256, 0, stream>>>((float4*)hbuf, stats, gamma, beta, nNodes);
}

// Round 11
// 203.463 us; speedup vs baseline: 1.6420x; 1.1950x over previous
//
#include <hip/hip_runtime.h>

#define F 64
#define BN_EPS 1e-5f
#define NBLK 1024          // edge chunks for counting sort
#define BSH 7              // bucket = row >> 7 (128 rows/bucket)

typedef __attribute__((ext_vector_type(8))) short bf16x8;
typedef __attribute__((ext_vector_type(4))) float f32x4;

static __device__ __forceinline__ float4 f4add(float4 a, float4 b) {
    a.x += b.x; a.y += b.y; a.z += b.z; a.w += b.w; return a;
}

// f32 -> bf16 round-to-nearest-even
static __device__ __forceinline__ short f2bf(float x) {
    union { float f; unsigned u; } v; v.f = x;
    const unsigned r = (v.u + 0x7fffu + ((v.u >> 16) & 1u)) >> 16;
    return (short)r;
}

// ---------------- P1: per-chunk bucket histogram (LDS only) ----------------
__global__ __launch_bounds__(256) void p1_count(
    const int* __restrict__ row,
    const int* __restrict__ col,
    int* __restrict__ cnt,          // [NBLK][NB]
    int nEdges, int NB, int C)
{
    __shared__ int hist[1024];      // NB <= 1024 (N <= 131072)
    const int t = threadIdx.x;
    const int b = blockIdx.x;
    for (int u = t; u < NB; u += 256) hist[u] = 0;
    __syncthreads();
    const int e0 = b * C;
    const int e1 = min(e0 + C, nEdges);
    for (int e = e0 + t; e < e1; e += 256) {
        const int r = row[e];
        const int c = col[e];
        if (r != c) atomicAdd(&hist[r >> BSH], 1);
    }
    __syncthreads();
    for (int u = t; u < NB; u += 256) cnt[(size_t)b * NB + u] = hist[u];
}

// ---------------- P2a: column scan of cnt (one block per bucket) -------------
__global__ __launch_bounds__(256) void p2a_colscan(
    int* __restrict__ cnt,          // in: counts, out: per-block exclusive prefix
    int* __restrict__ colsum,       // [NB] bucket totals
    int NB)
{
    __shared__ int vals[NBLK];
    __shared__ int part[256];
    const int u = blockIdx.x;
    const int t = threadIdx.x;
    for (int i = t; i < NBLK; i += 256) vals[i] = cnt[(size_t)i * NB + u];
    __syncthreads();
    int tmp[NBLK / 256];
    int s = 0;
    #pragma unroll
    for (int j = 0; j < NBLK / 256; ++j) { tmp[j] = s; s += vals[t * (NBLK / 256) + j]; }
    part[t] = s;
    __syncthreads();
    for (int off = 1; off < 256; off <<= 1) {
        const int a = (t >= off) ? part[t - off] : 0;
        __syncthreads();
        part[t] += a;
        __syncthreads();
    }
    const int prefix = part[t] - s;   // exclusive over threads
    #pragma unroll
    for (int j = 0; j < NBLK / 256; ++j) vals[t * (NBLK / 256) + j] = prefix + tmp[j];
    __syncthreads();
    for (int i = t; i < NBLK; i += 256) cnt[(size_t)i * NB + u] = vals[i];
    if (t == 255) colsum[u] = part[255];
}

// ---------------- P2b: scan bucket totals -> gstart (single block) -----------
__global__ __launch_bounds__(1024) void p2b_scan(
    const int* __restrict__ colsum,
    int* __restrict__ gstart,       // [NB+1]
    int* __restrict__ starts,       // write starts[n] = total
    int NB, int n)
{
    __shared__ int tmp[1024];
    const int t = threadIdx.x;
    const int v = (t < NB) ? colsum[t] : 0;
    tmp[t] = v;
    __syncthreads();
    for (int off = 1; off < 1024; off <<= 1) {
        const int a = (t >= off) ? tmp[t - off] : 0;
        __syncthreads();
        tmp[t] += a;
        __syncthreads();
    }
    if (t < NB) gstart[t] = tmp[t] - v;
    if (t == 1023) { gstart[NB] = tmp[1023]; starts[n] = tmp[1023]; }
}

// ---------------- P3: scatter edges into bucket-grouped packed array ---------
__global__ __launch_bounds__(256) void p3_scatter(
    const int* __restrict__ row,
    const int* __restrict__ col,
    const int* __restrict__ cnt,    // per-block exclusive prefix (from P2a)
    const int* __restrict__ gstart,
    unsigned* __restrict__ packed,  // (row&127)<<25 | col
    int nEdges, int NB, int C)
{
    __shared__ int cur[1024];
    const int t = threadIdx.x;
    const int b = blockIdx.x;
    for (int u = t; u < NB; u += 256) cur[u] = gstart[u] + cnt[(size_t)b * NB + u];
    __syncthreads();
    const int e0 = b * C;
    const int e1 = min(e0 + C, nEdges);
    for (int e = e0 + t; e < e1; e += 256) {
        const int r = row[e];
        const int c = col[e];
        if (r != c) {
            const int slot = atomicAdd(&cur[r >> BSH], 1);
            packed[slot] = ((unsigned)(r & 127) << 25) | (unsigned)c;
        }
    }
}

// ---------------- P4: per-bucket counting sort -> CSR (starts, col_sorted) ---
__global__ __launch_bounds__(256) void p4_sort(
    const unsigned* __restrict__ packed,
    const int* __restrict__ gstart,
    int* __restrict__ starts,
    int* __restrict__ col_sorted,
    int nNodes, int NB)
{
    __shared__ int hist[128];
    __shared__ int sc[128];
    const int t = threadIdx.x;
    const int u = blockIdx.x;
    const int e0 = gstart[u];
    const int e1 = gstart[u + 1];
    if (t < 128) hist[t] = 0;
    __syncthreads();
    for (int e = e0 + t; e < e1; e += 256) atomicAdd(&hist[packed[e] >> 25], 1);
    __syncthreads();
    if (t < 128) sc[t] = hist[t];
    __syncthreads();
    for (int off = 1; off < 128; off <<= 1) {
        int a = 0;
        if (t < 128 && t >= off) a = sc[t - off];
        __syncthreads();
        if (t < 128) sc[t] += a;
        __syncthreads();
    }
    if (t < 128) {
        const int st = e0 + sc[t] - hist[t];   // exclusive start of row u*128+t
        sc[t] = st;                            // reuse as cursor
        const int node = u * 128 + t;
        if (node < nNodes) starts[node] = st;
    }
    __syncthreads();
    for (int e = e0 + t; e < e1; e += 256) {
        const unsigned p = packed[e];
        const int slot = atomicAdd(&sc[p >> 25], 1);
        col_sorted[slot] = (int)(p & 0x1FFFFFFu);
    }
}

// ---------------- Kernel A: gather-aggregate (float4, direct index loads) -----
__global__ __launch_bounds__(256) void gather_kernel(
    const float4* __restrict__ x4,
    const int* __restrict__ starts,
    const int* __restrict__ col_sorted,
    float4* __restrict__ agg4,     // = d_out viewed as float4
    int nNodes)
{
    const int lane = threadIdx.x & 63;
    const int w = threadIdx.x >> 6;
    const int r = blockIdx.x * 4 + w;
    if (r >= nNodes) return;

    const int g = lane >> 4;   // 0..3
    const int q = lane & 15;   // 0..15

    const int s  = starts[r];
    const int en = starts[r + 1];

    const float4 vself = x4[(size_t)r * 16 + q];

    float4 a0 = {0,0,0,0}, a1 = {0,0,0,0}, a2 = {0,0,0,0}, a3 = {0,0,0,0};

    int e = s;
    for (; e + 16 <= en; e += 16) {
        const int c0 = col_sorted[e + g];
        const int c1 = col_sorted[e + 4 + g];
        const int c2 = col_sorted[e + 8 + g];
        const int c3 = col_sorted[e + 12 + g];
        const float4 t0 = x4[(size_t)c0 * 16 + q];
        const float4 t1 = x4[(size_t)c1 * 16 + q];
        const float4 t2 = x4[(size_t)c2 * 16 + q];
        const float4 t3 = x4[(size_t)c3 * 16 + q];
        a0 = f4add(a0, t0);
        a1 = f4add(a1, t1);
        a2 = f4add(a2, t2);
        a3 = f4add(a3, t3);
    }
    for (; e + 4 <= en; e += 4) {
        const int c = col_sorted[e + g];
        a0 = f4add(a0, x4[(size_t)c * 16 + q]);
    }
    if (e + g < en) {
        const int c = col_sorted[e + g];
        a1 = f4add(a1, x4[(size_t)c * 16 + q]);
    }

    float4 v = f4add(f4add(a0, a1), f4add(a2, a3));
    v.x += __shfl_xor(v.x, 16, 64);
    v.y += __shfl_xor(v.y, 16, 64);
    v.z += __shfl_xor(v.z, 16, 64);
    v.w += __shfl_xor(v.w, 16, 64);
    v.x += __shfl_xor(v.x, 32, 64);
    v.y += __shfl_xor(v.y, 32, 64);
    v.z += __shfl_xor(v.z, 32, 64);
    v.w += __shfl_xor(v.w, 32, 64);
    v = f4add(v, vself);

    if (g == 0) {
        agg4[(size_t)r * 16 + q] = v;
    }
}

// ---------------- Kernel B: MFMA bf16 MLP (64 nodes/block, 16/wave) -----------
__global__ __launch_bounds__(256) void mlp_kernel(
    const float* in_,               // = d_out (agg) — same buffer as out_
    const float* __restrict__ W1,
    const float* __restrict__ b1,
    const float* __restrict__ W2,
    const float* __restrict__ b2,
    float* out_,                    // = d_out (h2)
    int nNodes)
{
    __shared__ float sH[4][16][68];   // per-wave h1 [node][feat], padded

    const int tid  = threadIdx.x;
    const int lane = tid & 63;
    const int w    = tid >> 6;
    const int nb   = lane & 15;
    const int kg   = lane >> 4;
    const int kb   = kg * 8;

    bf16x8 w1f[2][4], w2f[2][4];
    #pragma unroll
    for (int s = 0; s < 2; ++s) {
        #pragma unroll
        for (int c = 0; c < 4; ++c) {
            #pragma unroll
            for (int e = 0; e < 8; ++e) {
                const int k = s * 32 + kb + e;
                w1f[s][c][e] = f2bf(W1[k * 64 + c * 16 + nb]);
                w2f[s][c][e] = f2bf(W2[k * 64 + c * 16 + nb]);
            }
        }
    }

    const int node0 = blockIdx.x * 64 + w * 16;

    int an = node0 + nb;
    if (an >= nNodes) an = nNodes - 1;
    const float* arow = in_ + (size_t)an * 64;
    bf16x8 a[2];
    #pragma unroll
    for (int s = 0; s < 2; ++s)
        #pragma unroll
        for (int e = 0; e < 8; ++e)
            a[s][e] = f2bf(arow[s * 32 + kb + e]);

    #pragma unroll
    for (int c = 0; c < 4; ++c) {
        const float bias = b1[c * 16 + nb];
        f32x4 acc = {bias, bias, bias, bias};
        acc = __builtin_amdgcn_mfma_f32_16x16x32_bf16(a[0], w1f[0][c], acc, 0, 0, 0);
        acc = __builtin_amdgcn_mfma_f32_16x16x32_bf16(a[1], w1f[1][c], acc, 0, 0, 0);
        #pragma unroll
        for (int r = 0; r < 4; ++r)
            sH[w][kg * 4 + r][c * 16 + nb] = fmaxf(acc[r], 0.0f);
    }
    __syncthreads();

    bf16x8 h[2];
    #pragma unroll
    for (int s = 0; s < 2; ++s)
        #pragma unroll
        for (int e = 0; e < 8; ++e)
            h[s][e] = f2bf(sH[w][nb][s * 32 + kb + e]);

    #pragma unroll
    for (int c = 0; c < 4; ++c) {
        const float bias = b2[c * 16 + nb];
        f32x4 acc = {bias, bias, bias, bias};
        acc = __builtin_amdgcn_mfma_f32_16x16x32_bf16(h[0], w2f[0][c], acc, 0, 0, 0);
        acc = __builtin_amdgcn_mfma_f32_16x16x32_bf16(h[1], w2f[1][c], acc, 0, 0, 0);
        #pragma unroll
        for (int r = 0; r < 4; ++r) {
            const int node = node0 + kg * 4 + r;
            if (node < nNodes)
                out_[(size_t)node * 64 + c * 16 + nb] = fmaxf(acc[r], 0.0f);
        }
    }
}

// ---------------- Kernel C1: BN stats (sum / sumsq per feature) ---------------
__global__ __launch_bounds__(256) void stats_kernel(
    const float4* __restrict__ h,
    float* __restrict__ stats,      // [0..63]=sum, [64..127]=sumsq, pre-zeroed
    int total4)
{
    float4 ps = {0,0,0,0}, pq = {0,0,0,0};
    const int stride = gridDim.x * blockDim.x;   // multiple of 16
    for (int i = blockIdx.x * blockDim.x + threadIdx.x; i < total4; i += stride) {
        const float4 v = h[i];
        ps.x += v.x; ps.y += v.y; ps.z += v.z; ps.w += v.w;
        pq.x = fmaf(v.x, v.x, pq.x);
        pq.y = fmaf(v.y, v.y, pq.y);
        pq.z = fmaf(v.z, v.z, pq.z);
        pq.w = fmaf(v.w, v.w, pq.w);
    }
    __shared__ float4 sS[256];
    __shared__ float4 sQ[256];
    sS[threadIdx.x] = ps;
    sQ[threadIdx.x] = pq;
    __syncthreads();
    if (threadIdx.x < 16) {
        const int c = threadIdx.x;
        float4 a = sS[c], b = sQ[c];
        for (int u = 1; u < 16; ++u) {
            a = f4add(a, sS[c + u * 16]);
            b = f4add(b, sQ[c + u * 16]);
        }
        atomicAdd(&stats[c * 4 + 0], a.x);
        atomicAdd(&stats[c * 4 + 1], a.y);
        atomicAdd(&stats[c * 4 + 2], a.z);
        atomicAdd(&stats[c * 4 + 3], a.w);
        atomicAdd(&stats[64 + c * 4 + 0], b.x);
        atomicAdd(&stats[64 + c * 4 + 1], b.y);
        atomicAdd(&stats[64 + c * 4 + 2], b.z);
        atomicAdd(&stats[64 + c * 4 + 3], b.w);
    }
}

// ---------------- Kernel C2: BN finalize + normalize in place (float4) --------
__global__ __launch_bounds__(256) void bn_normalize_kernel(
    float4* __restrict__ h,
    const float* __restrict__ stats,
    const float* __restrict__ gamma,
    const float* __restrict__ beta,
    int nNodes)
{
    __shared__ float sscale[F];
    __shared__ float sshift[F];
    if (threadIdx.x < F) {
        const int f = threadIdx.x;
        const float invN = 1.0f / (float)nNodes;
        const float mean = stats[f] * invN;
        const float var  = stats[F + f] * invN - mean * mean;
        const float inv  = rsqrtf(var + BN_EPS);
        const float g    = gamma[f];
        sscale[f] = inv * g;
        sshift[f] = beta[f] - mean * inv * g;
    }
    __syncthreads();

    const int total4 = nNodes * (F / 4);
    const int stride = gridDim.x * blockDim.x;
    for (int i = blockIdx.x * blockDim.x + threadIdx.x; i < total4; i += stride) {
        const int f0 = (i & 15) * 4;
        float4 v = h[i];
        v.x = fmaf(v.x, sscale[f0 + 0], sshift[f0 + 0]);
        v.y = fmaf(v.y, sscale[f0 + 1], sshift[f0 + 1]);
        v.z = fmaf(v.z, sscale[f0 + 2], sshift[f0 + 2]);
        v.w = fmaf(v.w, sscale[f0 + 3], sshift[f0 + 3]);
        h[i] = v;
    }
}

extern "C" void kernel_launch(void* const* d_in, const int* in_sizes, int n_in,
                              void* d_out, int out_size, void* d_ws, size_t ws_size,
                              hipStream_t stream)
{
    const float* x     = (const float*)d_in[0];
    const int*   eidx  = (const int*)d_in[1];   // [2, E]: row then col
    const float* W1    = (const float*)d_in[2];
    const float* b1    = (const float*)d_in[3];
    const float* W2    = (const float*)d_in[4];
    const float* b2    = (const float*)d_in[5];
    const float* gamma = (const float*)d_in[6];
    const float* beta  = (const float*)d_in[7];

    const int nNodes = in_sizes[0] / F;
    const int nEdges = in_sizes[1] / 2;
    const int* row = eidx;
    const int* col = eidx + nEdges;

    const int NB = (nNodes + 127) >> BSH;      // buckets (<= 1024 for N <= 131072)
    const int C  = (nEdges + NBLK - 1) / NBLK; // edges per chunk

    // workspace layout (4-byte elems)
    char* wsp = (char*)d_ws;
    float*    stats      = (float*)wsp;        wsp += 128 * 4;
    int*      gstart     = (int*)wsp;          wsp += 1056 * 4;             // NB+1
    int*      colsum     = (int*)wsp;          wsp += 1024 * 4;             // NB
    int*      starts     = (int*)wsp;          wsp += (size_t)(nNodes + 1) * 4;
    unsigned* packed     = (unsigned*)wsp;     wsp += (size_t)nEdges * 4;
    int*      cntX       = (int*)wsp;          // max(NBLK*NB, nEdges+16): cnt, then col_sorted
    int*      cnt        = cntX;
    int*      col_sorted = cntX;               // aliases cnt (cnt dead after P3)
    float* hbuf = (float*)d_out;               // agg, then h2, then final out

    hipMemsetAsync(stats, 0, 128 * 4, stream);

    p1_count  <<<NBLK, 256, 0, stream>>>(row, col, cnt, nEdges, NB, C);
    p2a_colscan<<<NB, 256, 0, stream>>>(cnt, colsum, NB);
    p2b_scan  <<<1, 1024, 0, stream>>>(colsum, gstart, starts, NB, nNodes);
    p3_scatter<<<NBLK, 256, 0, stream>>>(row, col, cnt, gstart, packed, nEdges, NB, C);
    p4_sort   <<<NB, 256, 0, stream>>>(packed, gstart, starts, col_sorted, nNodes, NB);

    gather_kernel<<<(nNodes + 3) / 4, 256, 0, stream>>>(
        (const float4*)x, starts, col_sorted, (float4*)hbuf, nNodes);

    mlp_kernel<<<(nNodes + 63) / 64, 256, 0, stream>>>(
        hbuf, W1, b1, W2, b2, hbuf, nNodes);

    stats_kernel<<<512, 256, 0, stream>>>((const float4*)hbuf, stats, nNodes * (F / 4));
    bn_normalize_kernel<<<2048, 256, 0, stream>>>((float4*)hbuf, stats, gamma, beta, nNodes);
}

// Round 12
// 195.080 us; speedup vs baseline: 1.7125x; 1.0430x over previous
//
#include <hip/hip_runtime.h>

#define F 64
#define BN_EPS 1e-5f
#define NBLK 1024          // edge chunks for counting sort
#define BSH 7              // bucket = row >> 7 (128 rows/bucket)

typedef __attribute__((ext_vector_type(8))) short bf16x8;
typedef __attribute__((ext_vector_type(4))) float f32x4;

static __device__ __forceinline__ float4 f4add(float4 a, float4 b) {
    a.x += b.x; a.y += b.y; a.z += b.z; a.w += b.w; return a;
}

// f32 -> bf16 round-to-nearest-even
static __device__ __forceinline__ unsigned short f2bf(float x) {
    union { float f; unsigned u; } v; v.f = x;
    return (unsigned short)((v.u + 0x7fffu + ((v.u >> 16) & 1u)) >> 16);
}
static __device__ __forceinline__ float bf2f(unsigned short u) {
    union { unsigned u; float f; } v; v.u = (unsigned)u << 16; return v.f;
}

// ---------------- P0: convert x to bf16 (into d_out lower half) --------------
__global__ __launch_bounds__(256) void cvt_kernel(
    const float4* __restrict__ x4,
    ushort4* __restrict__ xb4,
    int total4)
{
    const int stride = gridDim.x * blockDim.x;
    for (int i = blockIdx.x * blockDim.x + threadIdx.x; i < total4; i += stride) {
        const float4 v = x4[i];
        ushort4 o;
        o.x = f2bf(v.x); o.y = f2bf(v.y); o.z = f2bf(v.z); o.w = f2bf(v.w);
        xb4[i] = o;
    }
}

// ---------------- P1: per-chunk bucket histogram (LDS only) ----------------
__global__ __launch_bounds__(256) void p1_count(
    const int* __restrict__ row,
    const int* __restrict__ col,
    int* __restrict__ cnt,          // [NBLK][NB]
    int nEdges, int NB, int C)
{
    __shared__ int hist[1024];      // NB <= 1024
    const int t = threadIdx.x;
    const int b = blockIdx.x;
    for (int u = t; u < NB; u += 256) hist[u] = 0;
    __syncthreads();
    const int e0 = b * C;
    const int e1 = min(e0 + C, nEdges);
    for (int e = e0 + t; e < e1; e += 256) {
        const int r = row[e];
        const int c = col[e];
        if (r != c) atomicAdd(&hist[r >> BSH], 1);
    }
    __syncthreads();
    for (int u = t; u < NB; u += 256) cnt[(size_t)b * NB + u] = hist[u];
}

// ---------------- P2a: column scan of cnt (one block per bucket) -------------
__global__ __launch_bounds__(256) void p2a_colscan(
    int* __restrict__ cnt,
    int* __restrict__ colsum,
    int NB)
{
    __shared__ int vals[NBLK];
    __shared__ int part[256];
    const int u = blockIdx.x;
    const int t = threadIdx.x;
    for (int i = t; i < NBLK; i += 256) vals[i] = cnt[(size_t)i * NB + u];
    __syncthreads();
    int tmp[NBLK / 256];
    int s = 0;
    #pragma unroll
    for (int j = 0; j < NBLK / 256; ++j) { tmp[j] = s; s += vals[t * (NBLK / 256) + j]; }
    part[t] = s;
    __syncthreads();
    for (int off = 1; off < 256; off <<= 1) {
        const int a = (t >= off) ? part[t - off] : 0;
        __syncthreads();
        part[t] += a;
        __syncthreads();
    }
    const int prefix = part[t] - s;
    #pragma unroll
    for (int j = 0; j < NBLK / 256; ++j) vals[t * (NBLK / 256) + j] = prefix + tmp[j];
    __syncthreads();
    for (int i = t; i < NBLK; i += 256) cnt[(size_t)i * NB + u] = vals[i];
    if (t == 255) colsum[u] = part[255];
}

// ---------------- P2b: scan bucket totals -> gstart (single block) -----------
__global__ __launch_bounds__(1024) void p2b_scan(
    const int* __restrict__ colsum,
    int* __restrict__ gstart,
    int* __restrict__ starts,
    int NB, int n)
{
    __shared__ int tmp[1024];
    const int t = threadIdx.x;
    const int v = (t < NB) ? colsum[t] : 0;
    tmp[t] = v;
    __syncthreads();
    for (int off = 1; off < 1024; off <<= 1) {
        const int a = (t >= off) ? tmp[t - off] : 0;
        __syncthreads();
        tmp[t] += a;
        __syncthreads();
    }
    if (t < NB) gstart[t] = tmp[t] - v;
    if (t == 1023) { gstart[NB] = tmp[1023]; starts[n] = tmp[1023]; }
}

// ---------------- P3: scatter edges into bucket-grouped packed array ---------
__global__ __launch_bounds__(256) void p3_scatter(
    const int* __restrict__ row,
    const int* __restrict__ col,
    const int* __restrict__ cnt,
    const int* __restrict__ gstart,
    unsigned* __restrict__ packed,  // (row&127)<<25 | col
    int nEdges, int NB, int C)
{
    __shared__ int cur[1024];
    const int t = threadIdx.x;
    const int b = blockIdx.x;
    for (int u = t; u < NB; u += 256) cur[u] = gstart[u] + cnt[(size_t)b * NB + u];
    __syncthreads();
    const int e0 = b * C;
    const int e1 = min(e0 + C, nEdges);
    for (int e = e0 + t; e < e1; e += 256) {
        const int r = row[e];
        const int c = col[e];
        if (r != c) {
            const int slot = atomicAdd(&cur[r >> BSH], 1);
            packed[slot] = ((unsigned)(r & 127) << 25) | (unsigned)c;
        }
    }
}

// ---------------- P4: per-bucket counting sort -> CSR (starts, col_sorted) ---
__global__ __launch_bounds__(256) void p4_sort(
    const unsigned* __restrict__ packed,
    const int* __restrict__ gstart,
    int* __restrict__ starts,
    int* __restrict__ col_sorted,
    int nNodes, int NB)
{
    __shared__ int hist[128];
    __shared__ int sc[128];
    const int t = threadIdx.x;
    const int u = blockIdx.x;
    const int e0 = gstart[u];
    const int e1 = gstart[u + 1];
    if (t < 128) hist[t] = 0;
    __syncthreads();
    for (int e = e0 + t; e < e1; e += 256) atomicAdd(&hist[packed[e] >> 25], 1);
    __syncthreads();
    if (t < 128) sc[t] = hist[t];
    __syncthreads();
    for (int off = 1; off < 128; off <<= 1) {
        int a = 0;
        if (t < 128 && t >= off) a = sc[t - off];
        __syncthreads();
        if (t < 128) sc[t] += a;
        __syncthreads();
    }
    if (t < 128) {
        const int st = e0 + sc[t] - hist[t];
        sc[t] = st;
        const int node = u * 128 + t;
        if (node < nNodes) starts[node] = st;
    }
    __syncthreads();
    for (int e = e0 + t; e < e1; e += 256) {
        const unsigned p = packed[e];
        const int slot = atomicAdd(&sc[p >> 25], 1);
        col_sorted[slot] = (int)(p & 0x1FFFFFFu);
    }
}

// ---------------- Kernel A: bf16 gather-aggregate (8B loads, f32 accum) -------
// One wave per node; group g = lane>>4 handles edges e+g, e+4+g, e+8+g, e+12+g;
// q = lane&15 selects the 8-byte feature quad. 16 row-loads in flight.
__global__ __launch_bounds__(256) void gather_kernel(
    const ushort4* __restrict__ xb4,     // bf16 x, [node][16 quads]
    const int* __restrict__ starts,
    const int* __restrict__ col_sorted,
    ushort4* __restrict__ aggb4,         // bf16 agg out (ws)
    int nNodes)
{
    const int lane = threadIdx.x & 63;
    const int w = threadIdx.x >> 6;
    const int r = blockIdx.x * 4 + w;
    if (r >= nNodes) return;

    const int g = lane >> 4;   // 0..3
    const int q = lane & 15;   // 0..15

    const int s  = starts[r];
    const int en = starts[r + 1];

    const ushort4 uself = xb4[(size_t)r * 16 + q];

    float4 a0 = {0,0,0,0}, a1 = {0,0,0,0}, a2 = {0,0,0,0}, a3 = {0,0,0,0};

    int e = s;
    for (; e + 16 <= en; e += 16) {
        const int c0 = col_sorted[e + g];
        const int c1 = col_sorted[e + 4 + g];
        const int c2 = col_sorted[e + 8 + g];
        const int c3 = col_sorted[e + 12 + g];
        const ushort4 t0 = xb4[(size_t)c0 * 16 + q];
        const ushort4 t1 = xb4[(size_t)c1 * 16 + q];
        const ushort4 t2 = xb4[(size_t)c2 * 16 + q];
        const ushort4 t3 = xb4[(size_t)c3 * 16 + q];
        a0.x += bf2f(t0.x); a0.y += bf2f(t0.y); a0.z += bf2f(t0.z); a0.w += bf2f(t0.w);
        a1.x += bf2f(t1.x); a1.y += bf2f(t1.y); a1.z += bf2f(t1.z); a1.w += bf2f(t1.w);
        a2.x += bf2f(t2.x); a2.y += bf2f(t2.y); a2.z += bf2f(t2.z); a2.w += bf2f(t2.w);
        a3.x += bf2f(t3.x); a3.y += bf2f(t3.y); a3.z += bf2f(t3.z); a3.w += bf2f(t3.w);
    }
    for (; e + 4 <= en; e += 4) {
        const int c = col_sorted[e + g];
        const ushort4 t = xb4[(size_t)c * 16 + q];
        a0.x += bf2f(t.x); a0.y += bf2f(t.y); a0.z += bf2f(t.z); a0.w += bf2f(t.w);
    }
    if (e + g < en) {
        const int c = col_sorted[e + g];
        const ushort4 t = xb4[(size_t)c * 16 + q];
        a1.x += bf2f(t.x); a1.y += bf2f(t.y); a1.z += bf2f(t.z); a1.w += bf2f(t.w);
    }

    float4 v = f4add(f4add(a0, a1), f4add(a2, a3));
    v.x += __shfl_xor(v.x, 16, 64);
    v.y += __shfl_xor(v.y, 16, 64);
    v.z += __shfl_xor(v.z, 16, 64);
    v.w += __shfl_xor(v.w, 16, 64);
    v.x += __shfl_xor(v.x, 32, 64);
    v.y += __shfl_xor(v.y, 32, 64);
    v.z += __shfl_xor(v.z, 32, 64);
    v.w += __shfl_xor(v.w, 32, 64);
    v.x += bf2f(uself.x);
    v.y += bf2f(uself.y);
    v.z += bf2f(uself.z);
    v.w += bf2f(uself.w);

    if (g == 0) {
        ushort4 o;
        o.x = f2bf(v.x); o.y = f2bf(v.y); o.z = f2bf(v.z); o.w = f2bf(v.w);
        aggb4[(size_t)r * 16 + q] = o;
    }
}

// ---------------- Kernel B: MFMA bf16 MLP (64 nodes/block, 16/wave) -----------
// A-fragment loads agg directly as bf16x8 (no conversion).
__global__ __launch_bounds__(256) void mlp_kernel(
    const unsigned short* __restrict__ aggbf,   // bf16 agg (ws)
    const float* __restrict__ W1,
    const float* __restrict__ b1,
    const float* __restrict__ W2,
    const float* __restrict__ b2,
    float* __restrict__ out_,                   // d_out (h2, f32)
    int nNodes)
{
    __shared__ float sH[4][16][68];   // per-wave h1 [node][feat], padded

    const int tid  = threadIdx.x;
    const int lane = tid & 63;
    const int w    = tid >> 6;
    const int nb   = lane & 15;
    const int kg   = lane >> 4;
    const int kb   = kg * 8;

    bf16x8 w1f[2][4], w2f[2][4];
    #pragma unroll
    for (int s = 0; s < 2; ++s) {
        #pragma unroll
        for (int c = 0; c < 4; ++c) {
            #pragma unroll
            for (int e = 0; e < 8; ++e) {
                const int k = s * 32 + kb + e;
                w1f[s][c][e] = (short)f2bf(W1[k * 64 + c * 16 + nb]);
                w2f[s][c][e] = (short)f2bf(W2[k * 64 + c * 16 + nb]);
            }
        }
    }

    const int node0 = blockIdx.x * 64 + w * 16;

    int an = node0 + nb;
    if (an >= nNodes) an = nNodes - 1;
    const unsigned short* arow = aggbf + (size_t)an * 64;
    bf16x8 a[2];
    a[0] = *reinterpret_cast<const bf16x8*>(arow + kb);
    a[1] = *reinterpret_cast<const bf16x8*>(arow + 32 + kb);

    #pragma unroll
    for (int c = 0; c < 4; ++c) {
        const float bias = b1[c * 16 + nb];
        f32x4 acc = {bias, bias, bias, bias};
        acc = __builtin_amdgcn_mfma_f32_16x16x32_bf16(a[0], w1f[0][c], acc, 0, 0, 0);
        acc = __builtin_amdgcn_mfma_f32_16x16x32_bf16(a[1], w1f[1][c], acc, 0, 0, 0);
        #pragma unroll
        for (int r = 0; r < 4; ++r)
            sH[w][kg * 4 + r][c * 16 + nb] = fmaxf(acc[r], 0.0f);
    }
    __syncthreads();

    bf16x8 h[2];
    #pragma unroll
    for (int s = 0; s < 2; ++s)
        #pragma unroll
        for (int e = 0; e < 8; ++e)
            h[s][e] = (short)f2bf(sH[w][nb][s * 32 + kb + e]);

    #pragma unroll
    for (int c = 0; c < 4; ++c) {
        const float bias = b2[c * 16 + nb];
        f32x4 acc = {bias, bias, bias, bias};
        acc = __builtin_amdgcn_mfma_f32_16x16x32_bf16(h[0], w2f[0][c], acc, 0, 0, 0);
        acc = __builtin_amdgcn_mfma_f32_16x16x32_bf16(h[1], w2f[1][c], acc, 0, 0, 0);
        #pragma unroll
        for (int r = 0; r < 4; ++r) {
            const int node = node0 + kg * 4 + r;
            if (node < nNodes)
                out_[(size_t)node * 64 + c * 16 + nb] = fmaxf(acc[r], 0.0f);
        }
    }
}

// ---------------- Kernel C1: BN stats (sum / sumsq per feature) ---------------
__global__ __launch_bounds__(256) void stats_kernel(
    const float4* __restrict__ h,
    float* __restrict__ stats,
    int total4)
{
    float4 ps = {0,0,0,0}, pq = {0,0,0,0};
    const int stride = gridDim.x * blockDim.x;
    for (int i = blockIdx.x * blockDim.x + threadIdx.x; i < total4; i += stride) {
        const float4 v = h[i];
        ps.x += v.x; ps.y += v.y; ps.z += v.z; ps.w += v.w;
        pq.x = fmaf(v.x, v.x, pq.x);
        pq.y = fmaf(v.y, v.y, pq.y);
        pq.z = fmaf(v.z, v.z, pq.z);
        pq.w = fmaf(v.w, v.w, pq.w);
    }
    __shared__ float4 sS[256];
    __shared__ float4 sQ[256];
    sS[threadIdx.x] = ps;
    sQ[threadIdx.x] = pq;
    __syncthreads();
    if (threadIdx.x < 16) {
        const int c = threadIdx.x;
        float4 a = sS[c], b = sQ[c];
        for (int u = 1; u < 16; ++u) {
            a = f4add(a, sS[c + u * 16]);
            b = f4add(b, sQ[c + u * 16]);
        }
        atomicAdd(&stats[c * 4 + 0], a.x);
        atomicAdd(&stats[c * 4 + 1], a.y);
        atomicAdd(&stats[c * 4 + 2], a.z);
        atomicAdd(&stats[c * 4 + 3], a.w);
        atomicAdd(&stats[64 + c * 4 + 0], b.x);
        atomicAdd(&stats[64 + c * 4 + 1], b.y);
        atomicAdd(&stats[64 + c * 4 + 2], b.z);
        atomicAdd(&stats[64 + c * 4 + 3], b.w);
    }
}

// ---------------- Kernel C2: BN finalize + normalize in place (float4) --------
__global__ __launch_bounds__(256) void bn_normalize_kernel(
    float4* __restrict__ h,
    const float* __restrict__ stats,
    const float* __restrict__ gamma,
    const float* __restrict__ beta,
    int nNodes)
{
    __shared__ float sscale[F];
    __shared__ float sshift[F];
    if (threadIdx.x < F) {
        const int f = threadIdx.x;
        const float invN = 1.0f / (float)nNodes;
        const float mean = stats[f] * invN;
        const float var  = stats[F + f] * invN - mean * mean;
        const float inv  = rsqrtf(var + BN_EPS);
        const float g    = gamma[f];
        sscale[f] = inv * g;
        sshift[f] = beta[f] - mean * inv * g;
    }
    __syncthreads();

    const int total4 = nNodes * (F / 4);
    const int stride = gridDim.x * blockDim.x;
    for (int i = blockIdx.x * blockDim.x + threadIdx.x; i < total4; i += stride) {
        const int f0 = (i & 15) * 4;
        float4 v = h[i];
        v.x = fmaf(v.x, sscale[f0 + 0], sshift[f0 + 0]);
        v.y = fmaf(v.y, sscale[f0 + 1], sshift[f0 + 1]);
        v.z = fmaf(v.z, sscale[f0 + 2], sshift[f0 + 2]);
        v.w = fmaf(v.w, sscale[f0 + 3], sshift[f0 + 3]);
        h[i] = v;
    }
}

extern "C" void kernel_launch(void* const* d_in, const int* in_sizes, int n_in,
                              void* d_out, int out_size, void* d_ws, size_t ws_size,
                              hipStream_t stream)
{
    const float* x     = (const float*)d_in[0];
    const int*   eidx  = (const int*)d_in[1];   // [2, E]: row then col
    const float* W1    = (const float*)d_in[2];
    const float* b1    = (const float*)d_in[3];
    const float* W2    = (const float*)d_in[4];
    const float* b2    = (const float*)d_in[5];
    const float* gamma = (const float*)d_in[6];
    const float* beta  = (const float*)d_in[7];

    const int nNodes = in_sizes[0] / F;
    const int nEdges = in_sizes[1] / 2;
    const int* row = eidx;
    const int* col = eidx + nEdges;

    const int NB = (nNodes + 127) >> BSH;
    const int C  = (nEdges + NBLK - 1) / NBLK;

    // workspace layout (lifetime-aliased):
    //  [stats 512B][gstart][colsum][starts][cntX: cnt(P1-P3) -> col_sorted(P4-gather)]
    //  [packed(P3-P4) ... aggbf spans packed+6.4MB (gather-mlp; packed dead by then)]
    char* wsp = (char*)d_ws;
    float*    stats      = (float*)wsp;        wsp += 128 * 4;
    int*      gstart     = (int*)wsp;          wsp += 1056 * 4;
    int*      colsum     = (int*)wsp;          wsp += 1024 * 4;
    int*      starts     = (int*)wsp;          wsp += (size_t)(nNodes + 1) * 4;
    int*      cntX       = (int*)wsp;          wsp += (size_t)(nEdges + 16) * 4;
    int*      cnt        = cntX;
    int*      col_sorted = cntX;
    unsigned* packed     = (unsigned*)wsp;     // nEdges*4 bytes (dead after P4)
    unsigned short* aggbf = (unsigned short*)packed;  // nNodes*128 bytes (born in gather)

    // x_bf lives in d_out's lower half until gather completes; mlp/bn overwrite later
    ushort4* xb4 = (ushort4*)d_out;
    float* hbuf = (float*)d_out;

    hipMemsetAsync(stats, 0, 128 * 4, stream);

    cvt_kernel<<<2048, 256, 0, stream>>>((const float4*)x, xb4, nNodes * 16);

    p1_count  <<<NBLK, 256, 0, stream>>>(row, col, cnt, nEdges, NB, C);
    p2a_colscan<<<NB, 256, 0, stream>>>(cnt, colsum, NB);
    p2b_scan  <<<1, 1024, 0, stream>>>(colsum, gstart, starts, NB, nNodes);
    p3_scatter<<<NBLK, 256, 0, stream>>>(row, col, cnt, gstart, packed, nEdges, NB, C);
    p4_sort   <<<NB, 256, 0, stream>>>(packed, gstart, starts, col_sorted, nNodes, NB);

    gather_kernel<<<(nNodes + 3) / 4, 256, 0, stream>>>(
        (const ushort4*)xb4, starts, col_sorted, (ushort4*)aggbf, nNodes);

    mlp_kernel<<<(nNodes + 63) / 64, 256, 0, stream>>>(
        aggbf, W1, b1, W2, b2, hbuf, nNodes);

    stats_kernel<<<512, 256, 0, stream>>>((const float4*)hbuf, stats, nNodes * (F / 4));
    bn_normalize_kernel<<<2048, 256, 0, stream>>>((float4*)hbuf, stats, gamma, beta, nNodes);
}

// Round 13
// 144.910 us; speedup vs baseline: 2.3055x; 1.3462x over previous
//
#include <hip/hip_runtime.h>

#define F 64
#define BN_EPS 1e-5f
#define NBLK 1024          // edge chunks for counting sort
#define BSH 7              // bucket = row >> 7 (128 rows/bucket)
#define NSB 512            // stats partial blocks

typedef __attribute__((ext_vector_type(8))) short bf16x8;
typedef __attribute__((ext_vector_type(4))) float f32x4;

static __device__ __forceinline__ float4 f4add(float4 a, float4 b) {
    a.x += b.x; a.y += b.y; a.z += b.z; a.w += b.w; return a;
}

// f32 -> bf16 round-to-nearest-even
static __device__ __forceinline__ unsigned short f2bf(float x) {
    union { float f; unsigned u; } v; v.f = x;
    return (unsigned short)((v.u + 0x7fffu + ((v.u >> 16) & 1u)) >> 16);
}
static __device__ __forceinline__ float bf2f(unsigned short u) {
    union { unsigned u; float f; } v; v.u = (unsigned)u << 16; return v.f;
}

// ---------------- P0: convert x to bf16 (into d_out lower half) --------------
__global__ __launch_bounds__(256) void cvt_kernel(
    const float4* __restrict__ x4,
    ushort4* __restrict__ xb4,
    int total4)
{
    const int stride = gridDim.x * blockDim.x;
    for (int i = blockIdx.x * blockDim.x + threadIdx.x; i < total4; i += stride) {
        const float4 v = x4[i];
        ushort4 o;
        o.x = f2bf(v.x); o.y = f2bf(v.y); o.z = f2bf(v.z); o.w = f2bf(v.w);
        xb4[i] = o;
    }
}

// ---------------- P1: per-chunk bucket histogram (LDS only) ----------------
__global__ __launch_bounds__(256) void p1_count(
    const int* __restrict__ row,
    const int* __restrict__ col,
    int* __restrict__ cnt,          // [NBLK][NB]
    int nEdges, int NB, int C)
{
    __shared__ int hist[1024];      // NB <= 1024
    const int t = threadIdx.x;
    const int b = blockIdx.x;
    for (int u = t; u < NB; u += 256) hist[u] = 0;
    __syncthreads();
    const int e0 = b * C;
    const int e1 = min(e0 + C, nEdges);
    for (int e = e0 + t; e < e1; e += 256) {
        const int r = row[e];
        const int c = col[e];
        if (r != c) atomicAdd(&hist[r >> BSH], 1);
    }
    __syncthreads();
    for (int u = t; u < NB; u += 256) cnt[(size_t)b * NB + u] = hist[u];
}

// ---------------- P2a: column scan of cnt (one block per bucket) -------------
__global__ __launch_bounds__(256) void p2a_colscan(
    int* __restrict__ cnt,
    int* __restrict__ colsum,
    int NB)
{
    __shared__ int vals[NBLK];
    __shared__ int part[256];
    const int u = blockIdx.x;
    const int t = threadIdx.x;
    for (int i = t; i < NBLK; i += 256) vals[i] = cnt[(size_t)i * NB + u];
    __syncthreads();
    int tmp[NBLK / 256];
    int s = 0;
    #pragma unroll
    for (int j = 0; j < NBLK / 256; ++j) { tmp[j] = s; s += vals[t * (NBLK / 256) + j]; }
    part[t] = s;
    __syncthreads();
    for (int off = 1; off < 256; off <<= 1) {
        const int a = (t >= off) ? part[t - off] : 0;
        __syncthreads();
        part[t] += a;
        __syncthreads();
    }
    const int prefix = part[t] - s;
    #pragma unroll
    for (int j = 0; j < NBLK / 256; ++j) vals[t * (NBLK / 256) + j] = prefix + tmp[j];
    __syncthreads();
    for (int i = t; i < NBLK; i += 256) cnt[(size_t)i * NB + u] = vals[i];
    if (t == 255) colsum[u] = part[255];
}

// ---------------- P2b: scan bucket totals -> gstart (single block) -----------
__global__ __launch_bounds__(1024) void p2b_scan(
    const int* __restrict__ colsum,
    int* __restrict__ gstart,
    int* __restrict__ starts,
    int NB, int n)
{
    __shared__ int tmp[1024];
    const int t = threadIdx.x;
    const int v = (t < NB) ? colsum[t] : 0;
    tmp[t] = v;
    __syncthreads();
    for (int off = 1; off < 1024; off <<= 1) {
        const int a = (t >= off) ? tmp[t - off] : 0;
        __syncthreads();
        tmp[t] += a;
        __syncthreads();
    }
    if (t < NB) gstart[t] = tmp[t] - v;
    if (t == 1023) { gstart[NB] = tmp[1023]; starts[n] = tmp[1023]; }
}

// ---------------- P3: scatter edges into bucket-grouped packed array ---------
__global__ __launch_bounds__(256) void p3_scatter(
    const int* __restrict__ row,
    const int* __restrict__ col,
    const int* __restrict__ cnt,
    const int* __restrict__ gstart,
    unsigned* __restrict__ packed,  // (row&127)<<25 | col
    int nEdges, int NB, int C)
{
    __shared__ int cur[1024];
    const int t = threadIdx.x;
    const int b = blockIdx.x;
    for (int u = t; u < NB; u += 256) cur[u] = gstart[u] + cnt[(size_t)b * NB + u];
    __syncthreads();
    const int e0 = b * C;
    const int e1 = min(e0 + C, nEdges);
    for (int e = e0 + t; e < e1; e += 256) {
        const int r = row[e];
        const int c = col[e];
        if (r != c) {
            const int slot = atomicAdd(&cur[r >> BSH], 1);
            packed[slot] = ((unsigned)(r & 127) << 25) | (unsigned)c;
        }
    }
}

// ---------------- P4: per-bucket counting sort -> CSR (starts, col_sorted) ---
__global__ __launch_bounds__(256) void p4_sort(
    const unsigned* __restrict__ packed,
    const int* __restrict__ gstart,
    int* __restrict__ starts,
    int* __restrict__ col_sorted,
    int nNodes, int NB)
{
    __shared__ int hist[128];
    __shared__ int sc[128];
    const int t = threadIdx.x;
    const int u = blockIdx.x;
    const int e0 = gstart[u];
    const int e1 = gstart[u + 1];
    if (t < 128) hist[t] = 0;
    __syncthreads();
    for (int e = e0 + t; e < e1; e += 256) atomicAdd(&hist[packed[e] >> 25], 1);
    __syncthreads();
    if (t < 128) sc[t] = hist[t];
    __syncthreads();
    for (int off = 1; off < 128; off <<= 1) {
        int a = 0;
        if (t < 128 && t >= off) a = sc[t - off];
        __syncthreads();
        if (t < 128) sc[t] += a;
        __syncthreads();
    }
    if (t < 128) {
        const int st = e0 + sc[t] - hist[t];
        sc[t] = st;
        const int node = u * 128 + t;
        if (node < nNodes) starts[node] = st;
    }
    __syncthreads();
    for (int e = e0 + t; e < e1; e += 256) {
        const unsigned p = packed[e];
        const int slot = atomicAdd(&sc[p >> 25], 1);
        col_sorted[slot] = (int)(p & 0x1FFFFFFu);
    }
}

// ---------------- Kernel A: bf16 gather-aggregate (8B loads, f32 accum) -------
__global__ __launch_bounds__(256) void gather_kernel(
    const ushort4* __restrict__ xb4,     // bf16 x, [node][16 quads]
    const int* __restrict__ starts,
    const int* __restrict__ col_sorted,
    ushort4* __restrict__ aggb4,         // bf16 agg out (ws)
    int nNodes)
{
    const int lane = threadIdx.x & 63;
    const int w = threadIdx.x >> 6;
    const int r = blockIdx.x * 4 + w;
    if (r >= nNodes) return;

    const int g = lane >> 4;   // 0..3
    const int q = lane & 15;   // 0..15

    const int s  = starts[r];
    const int en = starts[r + 1];

    const ushort4 uself = xb4[(size_t)r * 16 + q];

    float4 a0 = {0,0,0,0}, a1 = {0,0,0,0}, a2 = {0,0,0,0}, a3 = {0,0,0,0};

    int e = s;
    for (; e + 16 <= en; e += 16) {
        const int c0 = col_sorted[e + g];
        const int c1 = col_sorted[e + 4 + g];
        const int c2 = col_sorted[e + 8 + g];
        const int c3 = col_sorted[e + 12 + g];
        const ushort4 t0 = xb4[(size_t)c0 * 16 + q];
        const ushort4 t1 = xb4[(size_t)c1 * 16 + q];
        const ushort4 t2 = xb4[(size_t)c2 * 16 + q];
        const ushort4 t3 = xb4[(size_t)c3 * 16 + q];
        a0.x += bf2f(t0.x); a0.y += bf2f(t0.y); a0.z += bf2f(t0.z); a0.w += bf2f(t0.w);
        a1.x += bf2f(t1.x); a1.y += bf2f(t1.y); a1.z += bf2f(t1.z); a1.w += bf2f(t1.w);
        a2.x += bf2f(t2.x); a2.y += bf2f(t2.y); a2.z += bf2f(t2.z); a2.w += bf2f(t2.w);
        a3.x += bf2f(t3.x); a3.y += bf2f(t3.y); a3.z += bf2f(t3.z); a3.w += bf2f(t3.w);
    }
    for (; e + 4 <= en; e += 4) {
        const int c = col_sorted[e + g];
        const ushort4 t = xb4[(size_t)c * 16 + q];
        a0.x += bf2f(t.x); a0.y += bf2f(t.y); a0.z += bf2f(t.z); a0.w += bf2f(t.w);
    }
    if (e + g < en) {
        const int c = col_sorted[e + g];
        const ushort4 t = xb4[(size_t)c * 16 + q];
        a1.x += bf2f(t.x); a1.y += bf2f(t.y); a1.z += bf2f(t.z); a1.w += bf2f(t.w);
    }

    float4 v = f4add(f4add(a0, a1), f4add(a2, a3));
    v.x += __shfl_xor(v.x, 16, 64);
    v.y += __shfl_xor(v.y, 16, 64);
    v.z += __shfl_xor(v.z, 16, 64);
    v.w += __shfl_xor(v.w, 16, 64);
    v.x += __shfl_xor(v.x, 32, 64);
    v.y += __shfl_xor(v.y, 32, 64);
    v.z += __shfl_xor(v.z, 32, 64);
    v.w += __shfl_xor(v.w, 32, 64);
    v.x += bf2f(uself.x);
    v.y += bf2f(uself.y);
    v.z += bf2f(uself.z);
    v.w += bf2f(uself.w);

    if (g == 0) {
        ushort4 o;
        o.x = f2bf(v.x); o.y = f2bf(v.y); o.z = f2bf(v.z); o.w = f2bf(v.w);
        aggb4[(size_t)r * 16 + q] = o;
    }
}

// ---------------- Kernel B: MFMA bf16 MLP (64 nodes/block, 16/wave) -----------
__global__ __launch_bounds__(256) void mlp_kernel(
    const unsigned short* __restrict__ aggbf,   // bf16 agg (ws)
    const float* __restrict__ W1,
    const float* __restrict__ b1,
    const float* __restrict__ W2,
    const float* __restrict__ b2,
    float* __restrict__ out_,                   // d_out (h2, f32)
    int nNodes)
{
    __shared__ float sH[4][16][68];   // per-wave h1 [node][feat], padded

    const int tid  = threadIdx.x;
    const int lane = tid & 63;
    const int w    = tid >> 6;
    const int nb   = lane & 15;
    const int kg   = lane >> 4;
    const int kb   = kg * 8;

    bf16x8 w1f[2][4], w2f[2][4];
    #pragma unroll
    for (int s = 0; s < 2; ++s) {
        #pragma unroll
        for (int c = 0; c < 4; ++c) {
            #pragma unroll
            for (int e = 0; e < 8; ++e) {
                const int k = s * 32 + kb + e;
                w1f[s][c][e] = (short)f2bf(W1[k * 64 + c * 16 + nb]);
                w2f[s][c][e] = (short)f2bf(W2[k * 64 + c * 16 + nb]);
            }
        }
    }

    const int node0 = blockIdx.x * 64 + w * 16;

    int an = node0 + nb;
    if (an >= nNodes) an = nNodes - 1;
    const unsigned short* arow = aggbf + (size_t)an * 64;
    bf16x8 a[2];
    a[0] = *reinterpret_cast<const bf16x8*>(arow + kb);
    a[1] = *reinterpret_cast<const bf16x8*>(arow + 32 + kb);

    #pragma unroll
    for (int c = 0; c < 4; ++c) {
        const float bias = b1[c * 16 + nb];
        f32x4 acc = {bias, bias, bias, bias};
        acc = __builtin_amdgcn_mfma_f32_16x16x32_bf16(a[0], w1f[0][c], acc, 0, 0, 0);
        acc = __builtin_amdgcn_mfma_f32_16x16x32_bf16(a[1], w1f[1][c], acc, 0, 0, 0);
        #pragma unroll
        for (int r = 0; r < 4; ++r)
            sH[w][kg * 4 + r][c * 16 + nb] = fmaxf(acc[r], 0.0f);
    }
    __syncthreads();

    bf16x8 h[2];
    #pragma unroll
    for (int s = 0; s < 2; ++s)
        #pragma unroll
        for (int e = 0; e < 8; ++e)
            h[s][e] = (short)f2bf(sH[w][nb][s * 32 + kb + e]);

    #pragma unroll
    for (int c = 0; c < 4; ++c) {
        const float bias = b2[c * 16 + nb];
        f32x4 acc = {bias, bias, bias, bias};
        acc = __builtin_amdgcn_mfma_f32_16x16x32_bf16(h[0], w2f[0][c], acc, 0, 0, 0);
        acc = __builtin_amdgcn_mfma_f32_16x16x32_bf16(h[1], w2f[1][c], acc, 0, 0, 0);
        #pragma unroll
        for (int r = 0; r < 4; ++r) {
            const int node = node0 + kg * 4 + r;
            if (node < nNodes)
                out_[(size_t)node * 64 + c * 16 + nb] = fmaxf(acc[r], 0.0f);
        }
    }
}

// ---------------- Kernel C1: BN partial stats (no atomics) --------------------
// Block bid writes its 128 partials to partial[f][NSB] (feature-major rows).
__global__ __launch_bounds__(256) void stats_kernel(
    const float4* __restrict__ h,
    float* __restrict__ partial,    // [128][NSB]
    int total4)
{
    float4 ps = {0,0,0,0}, pq = {0,0,0,0};
    const int stride = gridDim.x * blockDim.x;
    for (int i = blockIdx.x * blockDim.x + threadIdx.x; i < total4; i += stride) {
        const float4 v = h[i];
        ps.x += v.x; ps.y += v.y; ps.z += v.z; ps.w += v.w;
        pq.x = fmaf(v.x, v.x, pq.x);
        pq.y = fmaf(v.y, v.y, pq.y);
        pq.z = fmaf(v.z, v.z, pq.z);
        pq.w = fmaf(v.w, v.w, pq.w);
    }
    __shared__ float4 sS[256];
    __shared__ float4 sQ[256];
    sS[threadIdx.x] = ps;
    sQ[threadIdx.x] = pq;
    __syncthreads();
    if (threadIdx.x < 16) {
        const int c = threadIdx.x;
        float4 a = sS[c], b = sQ[c];
        for (int u = 1; u < 16; ++u) {
            a = f4add(a, sS[c + u * 16]);
            b = f4add(b, sQ[c + u * 16]);
        }
        const int bid = blockIdx.x;
        partial[(c * 4 + 0) * NSB + bid] = a.x;
        partial[(c * 4 + 1) * NSB + bid] = a.y;
        partial[(c * 4 + 2) * NSB + bid] = a.z;
        partial[(c * 4 + 3) * NSB + bid] = a.w;
        partial[(64 + c * 4 + 0) * NSB + bid] = b.x;
        partial[(64 + c * 4 + 1) * NSB + bid] = b.y;
        partial[(64 + c * 4 + 2) * NSB + bid] = b.z;
        partial[(64 + c * 4 + 3) * NSB + bid] = b.w;
    }
}

// ---------------- Kernel C1b: reduce partials -> stats (deterministic) --------
__global__ __launch_bounds__(256) void stats_reduce(
    const float* __restrict__ partial,   // [128][NSB]
    float* __restrict__ stats)           // [128]
{
    __shared__ float red[256];
    const int f = blockIdx.x;            // 0..127
    const int t = threadIdx.x;
    red[t] = partial[f * NSB + t] + partial[f * NSB + 256 + t];
    __syncthreads();
    for (int off = 128; off > 0; off >>= 1) {
        if (t < off) red[t] += red[t + off];
        __syncthreads();
    }
    if (t == 0) stats[f] = red[0];
}

// ---------------- Kernel C2: BN finalize + normalize in place (float4) --------
__global__ __launch_bounds__(256) void bn_normalize_kernel(
    float4* __restrict__ h,
    const float* __restrict__ stats,
    const float* __restrict__ gamma,
    const float* __restrict__ beta,
    int nNodes)
{
    __shared__ float sscale[F];
    __shared__ float sshift[F];
    if (threadIdx.x < F) {
        const int f = threadIdx.x;
        const float invN = 1.0f / (float)nNodes;
        const float mean = stats[f] * invN;
        const float var  = stats[F + f] * invN - mean * mean;
        const float inv  = rsqrtf(var + BN_EPS);
        const float g    = gamma[f];
        sscale[f] = inv * g;
        sshift[f] = beta[f] - mean * inv * g;
    }
    __syncthreads();

    const int total4 = nNodes * (F / 4);
    const int stride = gridDim.x * blockDim.x;
    for (int i = blockIdx.x * blockDim.x + threadIdx.x; i < total4; i += stride) {
        const int f0 = (i & 15) * 4;
        float4 v = h[i];
        v.x = fmaf(v.x, sscale[f0 + 0], sshift[f0 + 0]);
        v.y = fmaf(v.y, sscale[f0 + 1], sshift[f0 + 1]);
        v.z = fmaf(v.z, sscale[f0 + 2], sshift[f0 + 2]);
        v.w = fmaf(v.w, sscale[f0 + 3], sshift[f0 + 3]);
        h[i] = v;
    }
}

extern "C" void kernel_launch(void* const* d_in, const int* in_sizes, int n_in,
                              void* d_out, int out_size, void* d_ws, size_t ws_size,
                              hipStream_t stream)
{
    const float* x     = (const float*)d_in[0];
    const int*   eidx  = (const int*)d_in[1];   // [2, E]: row then col
    const float* W1    = (const float*)d_in[2];
    const float* b1    = (const float*)d_in[3];
    const float* W2    = (const float*)d_in[4];
    const float* b2    = (const float*)d_in[5];
    const float* gamma = (const float*)d_in[6];
    const float* beta  = (const float*)d_in[7];

    const int nNodes = in_sizes[0] / F;
    const int nEdges = in_sizes[1] / 2;
    const int* row = eidx;
    const int* col = eidx + nEdges;

    const int NB = (nNodes + 127) >> BSH;
    const int C  = (nEdges + NBLK - 1) / NBLK;

    // workspace layout (lifetime-aliased); every buffer fully written each call
    char* wsp = (char*)d_ws;
    float*    stats      = (float*)wsp;        wsp += 128 * 4;
    float*    partial    = (float*)wsp;        wsp += 128 * NSB * 4;      // 256 KB
    int*      gstart     = (int*)wsp;          wsp += 1056 * 4;
    int*      colsum     = (int*)wsp;          wsp += 1024 * 4;
    int*      starts     = (int*)wsp;          wsp += (size_t)(nNodes + 1) * 4;
    int*      cntX       = (int*)wsp;          wsp += (size_t)(nEdges + 16) * 4;
    int*      cnt        = cntX;
    int*      col_sorted = cntX;
    unsigned* packed     = (unsigned*)wsp;     // nEdges*4 (dead after P4)
    unsigned short* aggbf = (unsigned short*)packed;  // nNodes*128 B (born in gather)

    ushort4* xb4 = (ushort4*)d_out;    // bf16 x in d_out until gather completes
    float* hbuf = (float*)d_out;

    cvt_kernel<<<2048, 256, 0, stream>>>((const float4*)x, xb4, nNodes * 16);

    p1_count  <<<NBLK, 256, 0, stream>>>(row, col, cnt, nEdges, NB, C);
    p2a_colscan<<<NB, 256, 0, stream>>>(cnt, colsum, NB);
    p2b_scan  <<<1, 1024, 0, stream>>>(colsum, gstart, starts, NB, nNodes);
    p3_scatter<<<NBLK, 256, 0, stream>>>(row, col, cnt, gstart, packed, nEdges, NB, C);
    p4_sort   <<<NB, 256, 0, stream>>>(packed, gstart, starts, col_sorted, nNodes, NB);

    gather_kernel<<<(nNodes + 3) / 4, 256, 0, stream>>>(
        (const ushort4*)xb4, starts, col_sorted, (ushort4*)aggbf, nNodes);

    mlp_kernel<<<(nNodes + 63) / 64, 256, 0, stream>>>(
        aggbf, W1, b1, W2, b2, hbuf, nNodes);

    stats_kernel<<<NSB, 256, 0, stream>>>((const float4*)hbuf, partial, nNodes * (F / 4));
    stats_reduce<<<128, 256, 0, stream>>>(partial, stats);
    bn_normalize_kernel<<<2048, 256, 0, stream>>>((float4*)hbuf, stats, gamma, beta, nNodes);
}